// Round 6
// baseline (1529.763 us; speedup 1.0000x reference)
//
#include <hip/hip_runtime.h>

#define F0 256
#define HD 128
#define NP 100352   // padded rows (784*128)

typedef unsigned short u16;
typedef __attribute__((ext_vector_type(8))) short short8;
typedef __attribute__((ext_vector_type(4))) float f32x4;

__device__ inline float bf2f(u16 u) {
    union { unsigned int i; float f; } v; v.i = ((unsigned int)u) << 16; return v.f;
}
__device__ inline u16 f2bf(float f) {
    union { float f; unsigned int i; } v; v.f = f;
    unsigned int r = v.i + 0x7FFF + ((v.i >> 16) & 1);
    return (u16)(r >> 16);
}

// 4-level butterfly over the 16-lane group (l&15)
__device__ inline float rsum16(float v) {
    v += __shfl_xor(v, 1); v += __shfl_xor(v, 2);
    v += __shfl_xor(v, 4); v += __shfl_xor(v, 8);
    return v;
}

#define GLOAD16(gp, lp) __builtin_amdgcn_global_load_lds( \
    (const __attribute__((address_space(1))) void*)(gp), \
    (__attribute__((address_space(3))) void*)(lp), 16, 0, 0)

// ---------------------------------------------------------------------------
// CSR build: hist(+rank) -> scan -> atomic-free scatter
// ---------------------------------------------------------------------------
__global__ void k_hist_rank(const int* __restrict__ row, int* __restrict__ counts,
                            int* __restrict__ rank, int E) {
    int e = blockIdx.x * blockDim.x + threadIdx.x;
    if (e < E) rank[e] = atomicAdd(&counts[row[e]], 1);
}

__global__ void k_scan_blk(const int* __restrict__ counts, int* __restrict__ scan_out,
                           int* __restrict__ partials, int n) {
    __shared__ int wsum[16];
    int t = threadIdx.x;
    int i = blockIdx.x * 1024 + t;
    int v = (i < n) ? counts[i] : 0;
    int lane = t & 63, w = t >> 6;
    #pragma unroll
    for (int off = 1; off < 64; off <<= 1) { int u = __shfl_up(v, off); if (lane >= off) v += u; }
    if (lane == 63) wsum[w] = v;
    __syncthreads();
    if (t < 16) {
        int s = wsum[t];
        #pragma unroll
        for (int off = 1; off < 16; off <<= 1) { int u = __shfl_up(s, off); if (t >= off) s += u; }
        wsum[t] = s;
    }
    __syncthreads();
    int add = (w > 0) ? wsum[w - 1] : 0;
    if (i < n) scan_out[i] = v + add;
    if (t == 1023) partials[blockIdx.x] = wsum[15];
}

__global__ void k_scan_part(int* partials, int nb) {
    __shared__ int ws2[2];
    int t = threadIdx.x;
    int v = (t < nb) ? partials[t] : 0;
    int lane = t & 63, w = t >> 6;
    #pragma unroll
    for (int off = 1; off < 64; off <<= 1) { int u = __shfl_up(v, off); if (lane >= off) v += u; }
    if (lane == 63) ws2[w] = v;
    __syncthreads();
    if (w == 1) v += ws2[0];
    if (t < nb) partials[t] = v;
}

__global__ void k_scan_add(int* __restrict__ row_ptr, const int* __restrict__ partials, int n) {
    int b = blockIdx.x;
    int i = b * 1024 + threadIdx.x;
    if (b == 0 && threadIdx.x == 0) row_ptr[0] = 0;
    int add = (b > 0) ? partials[b - 1] : 0;
    if (i < n) row_ptr[1 + i] += add;
}

__global__ void k_scatter_direct(const int* __restrict__ row, const int* __restrict__ ecol,
                                 const float* __restrict__ avals, const int* __restrict__ rank,
                                 const int* __restrict__ row_ptr, int2* __restrict__ cv, int E) {
    int e = blockIdx.x * blockDim.x + threadIdx.x;
    if (e >= E) return;
    int r = row[e];
    int c = __builtin_nontemporal_load(ecol + e);
    float v = __builtin_nontemporal_load(avals + e);
    int rk = __builtin_nontemporal_load(rank + e);
    int pos = row_ptr[r] + rk;
    cv[pos] = make_int2(c, __float_as_int(v));
}

// ---------------------------------------------------------------------------
// casts
// ---------------------------------------------------------------------------
__global__ void k_cast_x(const float* __restrict__ x, u16* __restrict__ xb, int total4) {
    int i = blockIdx.x * blockDim.x + threadIdx.x;
    if (i >= total4) return;
    float4 v = ((const float4*)x)[i];
    ((ushort4*)xb)[i] = make_ushort4(f2bf(v.x), f2bf(v.y), f2bf(v.z), f2bf(v.w));
}

__global__ void k_prep_w(const float* __restrict__ W_gc1, const float* __restrict__ W_gc2,
                         const float* __restrict__ Wg1, const float* __restrict__ Wxp,
                         const float* __restrict__ Wq, const float* __restrict__ Wk,
                         const float* __restrict__ Wv,
                         u16* Wgc1t, u16* Wgc2t, u16* Wdt, u16* W1t, u16* W2t,
                         u16* Wxpt, u16* Wqt, u16* Wkt, u16* Wvt) {
    int z = blockIdx.z;
    int idx = blockIdx.x * 256 + threadIdx.x;
    if (z == 0) { if (idx < 65536) { int n = idx >> 8, k = idx & 255; Wgc1t[idx] = f2bf(W_gc1[k * 256 + n]); } }
    else if (z == 1) { if (idx < 32768) { int n = idx >> 8, k = idx & 255; Wgc2t[idx] = f2bf(W_gc2[k * 128 + n]); } }
    else if (z == 2) { if (idx < 32768) { int n = idx >> 8, k = idx & 255; Wdt[idx] = f2bf(Wg1[k * 128 + n] - Wg1[(k + 256) * 128 + n]); } }
    else if (z == 3) { if (idx < 32768) { int n = idx >> 8, k = idx & 255; W1t[idx] = f2bf(Wg1[(k + 256) * 128 + n]); } }
    else if (z == 4) { if (idx < 32768) { int n = idx >> 8, k = idx & 255; W2t[idx] = f2bf(Wg1[(k + 512) * 128 + n]); } }
    else if (z == 5) { if (idx < 32768) { int n = idx >> 8, k = idx & 255; Wxpt[idx] = f2bf(Wxp[k * 128 + n]); } }
    else if (z == 6) { if (idx < 16384) { int n = idx >> 7, k = idx & 127; Wqt[idx] = f2bf(Wq[k * 128 + n]); } }
    else if (z == 7) { if (idx < 16384) { int n = idx >> 7, k = idx & 127; Wkt[idx] = f2bf(Wk[k * 128 + n]); } }
    else if (z == 8) { if (idx < 16384) { int n = idx >> 7, k = idx & 127; Wvt[idx] = f2bf(Wv[k * 128 + n]); } }
}

// ---------------------------------------------------------------------------
// SpMM over x with fused mean/std finalize (unroll-8)
// ---------------------------------------------------------------------------
__global__ void k_spmm_x2(const u16* __restrict__ Xb, const int* __restrict__ row_ptr,
                          const int2* __restrict__ cv,
                          u16* __restrict__ AXb, u16* __restrict__ XSTDb,
                          float* __restrict__ deg, int N) {
    int wid = blockIdx.x * 4 + (threadIdx.x >> 6);
    if (wid >= N) return;
    int lane = threadIdx.x & 63;
    float a0 = 0, a1 = 0, a2 = 0, a3 = 0;
    float q0 = 0, q1 = 0, q2 = 0, q3 = 0, d = 0;
    int s = row_ptr[wid], e = row_ptr[wid + 1];
    int j = s;
    for (; j + 7 < e; j += 8) {
        int2 cc[8]; ushort4 xb[8];
        #pragma unroll
        for (int t = 0; t < 8; ++t) cc[t] = cv[j + t];
        #pragma unroll
        for (int t = 0; t < 8; ++t) xb[t] = *(const ushort4*)(Xb + (size_t)cc[t].x * F0 + lane * 4);
        #pragma unroll
        for (int t = 0; t < 8; ++t) {
            float x0 = bf2f(xb[t].x), x1 = bf2f(xb[t].y), x2 = bf2f(xb[t].z), x3 = bf2f(xb[t].w);
            float vv = __int_as_float(cc[t].y);
            a0 += vv * x0; a1 += vv * x1; a2 += vv * x2; a3 += vv * x3;
            q0 += vv * x0 * x0; q1 += vv * x1 * x1; q2 += vv * x2 * x2; q3 += vv * x3 * x3;
            d += vv;
        }
    }
    for (; j < e; ++j) {
        int2 cc = cv[j];
        float v0 = __int_as_float(cc.y);
        ushort4 xb0 = *(const ushort4*)(Xb + (size_t)cc.x * F0 + lane * 4);
        float x0 = bf2f(xb0.x), x1 = bf2f(xb0.y), x2 = bf2f(xb0.z), x3 = bf2f(xb0.w);
        a0 += v0 * x0; a1 += v0 * x1; a2 += v0 * x2; a3 += v0 * x3;
        q0 += v0 * x0 * x0; q1 += v0 * x1 * x1; q2 += v0 * x2 * x2; q3 += v0 * x3 * x3;
        d += v0;
    }
    float inv = 1.0f / (d + 1e-8f);
    float m0 = a0 * inv, m1 = a1 * inv, m2 = a2 * inv, m3 = a3 * inv;
    float s0 = sqrtf(fmaxf(q0 * inv - m0 * m0, 0.f));
    float s1 = sqrtf(fmaxf(q1 * inv - m1 * m1, 0.f));
    float s2 = sqrtf(fmaxf(q2 * inv - m2 * m2, 0.f));
    float s3 = sqrtf(fmaxf(q3 * inv - m3 * m3, 0.f));
    *(ushort4*)(AXb + (size_t)wid * F0 + lane * 4) = make_ushort4(f2bf(a0), f2bf(a1), f2bf(a2), f2bf(a3));
    *(ushort4*)(XSTDb + (size_t)wid * F0 + lane * 4) = make_ushort4(f2bf(s0), f2bf(s1), f2bf(s2), f2bf(s3));
    if (lane == 0) deg[wid] = d;
}

// bf16 in, bf16 out (unroll-8)
__global__ void k_spmm128(const u16* __restrict__ Xb, const int* __restrict__ row_ptr,
                          const int2* __restrict__ cv, u16* __restrict__ OUT, int N) {
    int wid = blockIdx.x * 4 + (threadIdx.x >> 6);
    if (wid >= N) return;
    int lane = threadIdx.x & 63;
    float a0 = 0, a1 = 0;
    int s = row_ptr[wid], e = row_ptr[wid + 1];
    int j = s;
    for (; j + 7 < e; j += 8) {
        int2 cc[8]; ushort2 xb[8];
        #pragma unroll
        for (int t = 0; t < 8; ++t) cc[t] = cv[j + t];
        #pragma unroll
        for (int t = 0; t < 8; ++t) xb[t] = *(const ushort2*)(Xb + (size_t)cc[t].x * HD + lane * 2);
        #pragma unroll
        for (int t = 0; t < 8; ++t) {
            float vv = __int_as_float(cc[t].y);
            a0 += vv * bf2f(xb[t].x); a1 += vv * bf2f(xb[t].y);
        }
    }
    for (; j < e; ++j) {
        int2 cc = cv[j];
        float v0 = __int_as_float(cc.y);
        ushort2 x0 = *(const ushort2*)(Xb + (size_t)cc.x * HD + lane * 2);
        a0 += v0 * bf2f(x0.x); a1 += v0 * bf2f(x0.y);
    }
    *(ushort2*)(OUT + (size_t)wid * HD + lane * 2) = make_ushort2(f2bf(a0), f2bf(a1));
}

// ---------------------------------------------------------------------------
// bf16 MFMA GEMM core: C[128,128] tile = A[M,K] @ Bt[N,K]^T, BK=32
// ---------------------------------------------------------------------------
__device__ inline void mm_core(const u16* __restrict__ A, const u16* __restrict__ Bt,
                               int K, int ldA, int ldB, int m0, int n0,
                               u16* As, u16* Bs, f32x4 acc[4][4]) {
    int t = threadIdx.x, w = t >> 6, l = t & 63;
    int wr = (w >> 1) * 64, wc = (w & 1) * 64;
    int aoff = (wr + (l & 15)) * 32 + (l >> 4) * 8;
    int boff = (wc + (l & 15)) * 32 + (l >> 4) * 8;
    for (int k0 = 0; k0 < K; k0 += 32) {
        __syncthreads();
        #pragma unroll
        for (int s = 0; s < 2; ++s) {
            int i = s * 256 + t;
            int row = i >> 2, ch = i & 3;
            GLOAD16(A + (size_t)(m0 + row) * ldA + k0 + ch * 8, As + i * 8);
            GLOAD16(Bt + (size_t)(n0 + row) * ldB + k0 + ch * 8, Bs + i * 8);
        }
        __syncthreads();
        short8 af[4], bfr[4];
        #pragma unroll
        for (int i = 0; i < 4; ++i) af[i] = *(const short8*)(As + aoff + i * 16 * 32);
        #pragma unroll
        for (int j = 0; j < 4; ++j) bfr[j] = *(const short8*)(Bs + boff + j * 16 * 32);
        #pragma unroll
        for (int i = 0; i < 4; ++i)
            #pragma unroll
            for (int j = 0; j < 4; ++j)
                acc[i][j] = __builtin_amdgcn_mfma_f32_16x16x32_bf16(af[i], bfr[j], acc[i][j], 0, 0, 0);
    }
}

__device__ inline void mm_zero(f32x4 acc[4][4]) {
    #pragma unroll
    for (int i = 0; i < 4; ++i)
        #pragma unroll
        for (int j = 0; j < 4; ++j)
            acc[i][j] = (f32x4){0.f, 0.f, 0.f, 0.f};
}

__global__ __launch_bounds__(256) void k_mm_bf(const u16* __restrict__ A, const u16* __restrict__ Bt,
                                               u16* __restrict__ C, int M, int K, int Nc) {
    __shared__ __align__(16) u16 As[128 * 32];
    __shared__ __align__(16) u16 Bs[128 * 32];
    int m0 = blockIdx.x * 128, n0 = blockIdx.y * 128;
    f32x4 acc[4][4]; mm_zero(acc);
    mm_core(A, Bt, K, K, K, m0, n0, As, Bs, acc);
    int t = threadIdx.x, w = t >> 6, l = t & 63;
    int rbase = m0 + (w >> 1) * 64 + (l >> 4) * 4;
    int cbase = n0 + (w & 1) * 64 + (l & 15);
    #pragma unroll
    for (int j = 0; j < 4; ++j)
        #pragma unroll
        for (int i = 0; i < 4; ++i)
            #pragma unroll
            for (int r = 0; r < 4; ++r) {
                int row = rbase + i * 16 + r;
                if (row < M) C[(size_t)row * Nc + cbase + j * 16] = f2bf(acc[i][j][r]);
            }
}

// gating GEMM with fused row-LN + relu + Wg2 dot + softmax -> gate[N][2]
__global__ __launch_bounds__(256) void k_mm_gate(const u16* A0, const u16* A1, const u16* A2,
                                                 const u16* B0, const u16* B1, const u16* B2,
                                                 const float* __restrict__ bg1,
                                                 const float* __restrict__ wlast,
                                                 const float* __restrict__ deg,
                                                 const float* __restrict__ ln_g,
                                                 const float* __restrict__ ln_b,
                                                 const float* __restrict__ Wg2,
                                                 const float* __restrict__ bg2,
                                                 float* __restrict__ gate, int M) {
    __shared__ __align__(16) u16 As[128 * 32];
    __shared__ __align__(16) u16 Bs[128 * 32];
    __shared__ float ps1[2][128], ps2[2][128], pt0[2][128], pt1[2][128];
    int m0 = blockIdx.x * 128;
    f32x4 acc[4][4]; mm_zero(acc);
    mm_core(A0, B0, 256, 256, 256, m0, 0, As, Bs, acc);
    mm_core(A1, B1, 256, 256, 256, m0, 0, As, Bs, acc);
    mm_core(A2, B2, 256, 256, 256, m0, 0, As, Bs, acc);
    int t = threadIdx.x, w = t >> 6, l = t & 63;
    int hcol = w & 1;
    int lr0 = (w >> 1) * 64 + (l >> 4) * 4;
    int cbase = hcol * 64 + (l & 15);
    float wl[4], bg[4], lg[4], lb[4], wa[4], wb_[4];
    #pragma unroll
    for (int j = 0; j < 4; ++j) {
        int col = cbase + j * 16;
        wl[j] = wlast[col]; bg[j] = bg1[col];
        lg[j] = ln_g[col];  lb[j] = ln_b[col];
        wa[j] = Wg2[col * 2 + 0]; wb_[j] = Wg2[col * 2 + 1];
    }
    #pragma unroll
    for (int i = 0; i < 4; ++i)
        #pragma unroll
        for (int r = 0; r < 4; ++r) {
            int row = m0 + lr0 + i * 16 + r;
            float dgv = (row < M) ? deg[row] : 0.f;
            float s1 = 0.f, s2 = 0.f;
            #pragma unroll
            for (int j = 0; j < 4; ++j) {
                float h = acc[i][j][r] + bg[j] + dgv * wl[j];
                acc[i][j][r] = h;
                s1 += h; s2 += h * h;
            }
            s1 = rsum16(s1); s2 = rsum16(s2);
            if ((l & 15) == 0) { ps1[hcol][lr0 + i * 16 + r] = s1; ps2[hcol][lr0 + i * 16 + r] = s2; }
        }
    __syncthreads();
    #pragma unroll
    for (int i = 0; i < 4; ++i)
        #pragma unroll
        for (int r = 0; r < 4; ++r) {
            int lr = lr0 + i * 16 + r;
            float s1 = ps1[0][lr] + ps1[1][lr];
            float s2 = ps2[0][lr] + ps2[1][lr];
            float mu = s1 * (1.f / 128.f);
            float var = s2 * (1.f / 128.f) - mu * mu;
            float is = 1.0f / sqrtf(var + 1e-5f);
            float t0 = 0.f, t1 = 0.f;
            #pragma unroll
            for (int j = 0; j < 4; ++j) {
                float y = fmaxf((acc[i][j][r] - mu) * is * lg[j] + lb[j], 0.f);
                t0 += y * wa[j]; t1 += y * wb_[j];
            }
            t0 = rsum16(t0); t1 = rsum16(t1);
            if ((l & 15) == 0) { pt0[hcol][lr] = t0; pt1[hcol][lr] = t1; }
        }
    __syncthreads();
    if (hcol == 0 && (l & 15) == 0) {
        float b20 = bg2[0], b21 = bg2[1];
        #pragma unroll
        for (int i = 0; i < 4; ++i)
            #pragma unroll
            for (int r = 0; r < 4; ++r) {
                int lr = lr0 + i * 16 + r;
                int row = m0 + lr;
                if (row >= M) continue;
                float t0 = (pt0[0][lr] + pt0[1][lr] + b20) * 0.5f;
                float t1 = (pt1[0][lr] + pt1[1][lr] + b21) * 0.5f;
                float m = fmaxf(t0, t1);
                float e0 = __expf(t0 - m), e1 = __expf(t1 - m);
                float inv = 1.0f / (e0 + e1);
                gate[(size_t)row * 2 + 0] = e0 * inv;
                gate[(size_t)row * 2 + 1] = e1 * inv;
            }
    }
}

// x@Wxp+bxp with fused residual-LN -> resid (bf16)
__global__ __launch_bounds__(256) void k_mm_xp(const u16* __restrict__ A, const u16* __restrict__ Bt,
                                               const float* __restrict__ bias,
                                               const float* __restrict__ low,
                                               const float* __restrict__ g,
                                               const float* __restrict__ b,
                                               const float* __restrict__ rs_ptr,
                                               u16* __restrict__ resid, int M) {
    __shared__ __align__(16) u16 As[128 * 32];
    __shared__ __align__(16) u16 Bs[128 * 32];
    __shared__ float ps1[2][128], ps2[2][128];
    int m0 = blockIdx.x * 128;
    f32x4 acc[4][4]; mm_zero(acc);
    mm_core(A, Bt, 256, 256, 256, m0, 0, As, Bs, acc);
    int t = threadIdx.x, w = t >> 6, l = t & 63;
    int hcol = w & 1;
    int lr0 = (w >> 1) * 64 + (l >> 4) * 4;
    int cbase = hcol * 64 + (l & 15);
    float rs = rs_ptr[0];
    float bx[4], lg[4], lb[4];
    #pragma unroll
    for (int j = 0; j < 4; ++j) {
        int col = cbase + j * 16;
        bx[j] = bias[col]; lg[j] = g[col]; lb[j] = b[col];
    }
    #pragma unroll
    for (int i = 0; i < 4; ++i)
        #pragma unroll
        for (int r = 0; r < 4; ++r) {
            int row = m0 + lr0 + i * 16 + r;
            float s1 = 0.f, s2 = 0.f;
            #pragma unroll
            for (int j = 0; j < 4; ++j) {
                float lv = (row < M) ? low[(size_t)row * 128 + cbase + j * 16] : 0.f;
                float h = rs * (acc[i][j][r] + bx[j] - lv);
                acc[i][j][r] = h;
                s1 += h; s2 += h * h;
            }
            s1 = rsum16(s1); s2 = rsum16(s2);
            if ((l & 15) == 0) { ps1[hcol][lr0 + i * 16 + r] = s1; ps2[hcol][lr0 + i * 16 + r] = s2; }
        }
    __syncthreads();
    #pragma unroll
    for (int i = 0; i < 4; ++i)
        #pragma unroll
        for (int r = 0; r < 4; ++r) {
            int lr = lr0 + i * 16 + r;
            int row = m0 + lr;
            float s1 = ps1[0][lr] + ps1[1][lr];
            float s2 = ps2[0][lr] + ps2[1][lr];
            float mu = s1 * (1.f / 128.f);
            float var = s2 * (1.f / 128.f) - mu * mu;
            float is = 1.0f / sqrtf(var + 1e-5f);
            if (row < M) {
                #pragma unroll
                for (int j = 0; j < 4; ++j) {
                    float y = (acc[i][j][r] - mu) * is * lg[j] + lb[j];
                    resid[(size_t)row * 128 + cbase + j * 16] = f2bf(y);
                }
            }
        }
}

// fused QKV: stage the 128x128 A-tile (resid) into LDS ONCE, reuse for Q,K,V.
// Q -> bf16 Qb; K/V -> bf16 interleaved KV[N][256]
__global__ __launch_bounds__(256) void k_mm_qkv3(const u16* __restrict__ A,
                                                 const u16* __restrict__ Wqt,
                                                 const u16* __restrict__ Wkt,
                                                 const u16* __restrict__ Wvt,
                                                 u16* __restrict__ Qb, u16* __restrict__ KV, int M) {
    __shared__ __align__(16) u16 As[4][128 * 32];   // 4 k-chunks of A (32 KB)
    __shared__ __align__(16) u16 Bs[128 * 32];
    int m0 = blockIdx.x * 128;
    int t = threadIdx.x, w = t >> 6, l = t & 63;
    // stage full A tile (K=128): 16B x 16 per thread
    #pragma unroll
    for (int c = 0; c < 4; ++c)
        #pragma unroll
        for (int s = 0; s < 2; ++s) {
            int i = s * 256 + t;
            int row = i >> 2, ch = i & 3;
            GLOAD16(A + (size_t)(m0 + row) * 128 + c * 32 + ch * 8, As[c] + i * 8);
        }
    int wr = (w >> 1) * 64, wc = (w & 1) * 64;
    int aoff = (wr + (l & 15)) * 32 + (l >> 4) * 8;
    int boff = (wc + (l & 15)) * 32 + (l >> 4) * 8;
    int rbase = m0 + (w >> 1) * 64 + (l >> 4) * 4;
    int cbase = (w & 1) * 64 + (l & 15);
    #pragma unroll
    for (int z = 0; z < 3; ++z) {
        const u16* Bt = (z == 0) ? Wqt : (z == 1) ? Wkt : Wvt;
        f32x4 acc[4][4]; mm_zero(acc);
        for (int k0 = 0; k0 < 128; k0 += 32) {
            __syncthreads();   // waves done reading Bs (and A staged, first iter)
            #pragma unroll
            for (int s = 0; s < 2; ++s) {
                int i = s * 256 + t;
                int row = i >> 2, ch = i & 3;
                GLOAD16(Bt + (size_t)row * 128 + k0 + ch * 8, Bs + i * 8);
            }
            __syncthreads();
            const u16* Ac = As[k0 >> 5];
            short8 af[4], bfr[4];
            #pragma unroll
            for (int i = 0; i < 4; ++i) af[i] = *(const short8*)(Ac + aoff + i * 16 * 32);
            #pragma unroll
            for (int j = 0; j < 4; ++j) bfr[j] = *(const short8*)(Bs + boff + j * 16 * 32);
            #pragma unroll
            for (int i = 0; i < 4; ++i)
                #pragma unroll
                for (int j = 0; j < 4; ++j)
                    acc[i][j] = __builtin_amdgcn_mfma_f32_16x16x32_bf16(af[i], bfr[j], acc[i][j], 0, 0, 0);
        }
        if (z == 0) {
            #pragma unroll
            for (int j = 0; j < 4; ++j)
                #pragma unroll
                for (int i = 0; i < 4; ++i)
                    #pragma unroll
                    for (int r = 0; r < 4; ++r) {
                        int row = rbase + i * 16 + r;
                        if (row < M) Qb[(size_t)row * 128 + cbase + j * 16] = f2bf(acc[i][j][r]);
                    }
        } else {
            int coff = (z == 1) ? 0 : 128;
            #pragma unroll
            for (int j = 0; j < 4; ++j)
                #pragma unroll
                for (int i = 0; i < 4; ++i)
                    #pragma unroll
                    for (int r = 0; r < 4; ++r) {
                        int row = rbase + i * 16 + r;
                        if (row < M) KV[(size_t)row * 256 + coff + cbase + j * 16] = f2bf(acc[i][j][r]);
                    }
        }
    }
}

// ---------------------------------------------------------------------------
// BatchNorm (bf16 input)
// ---------------------------------------------------------------------------
__global__ void k_bn_stats_bf(const u16* __restrict__ H, double* __restrict__ stats, int N, int C) {
    int t = threadIdx.x;
    int rpt = 256 / C;
    int rsub = t / C;
    int col = t - rsub * C;
    double s = 0.0, q = 0.0;
    for (long r = (long)blockIdx.x * rpt + rsub; r < N; r += (long)gridDim.x * rpt) {
        float v = bf2f(H[(size_t)r * C + col]);
        s += v; q += (double)v * v;
    }
    __shared__ double sh_s[256], sh_q[256];
    sh_s[t] = s; sh_q[t] = q;
    __syncthreads();
    if (t < C) {
        for (int k = 1; k < rpt; ++k) { s += sh_s[t + k * C]; q += sh_q[t + k * C]; }
        atomicAdd(&stats[t], s);
        atomicAdd(&stats[C + t], q);
    }
}

__global__ void k_bn_fin(const double* __restrict__ stats, const float* __restrict__ g,
                         const float* __restrict__ b, float* __restrict__ scale,
                         float* __restrict__ shift, int C, double invN) {
    int t = threadIdx.x;
    if (t >= C) return;
    double mean = stats[t] * invN;
    double var = stats[C + t] * invN - mean * mean;
    float sc = (float)((double)g[t] / sqrt(var + 1e-5));
    scale[t] = sc;
    shift[t] = b[t] - (float)mean * sc;
}

__global__ void k_bn_relu_bb(const u16* __restrict__ in, u16* __restrict__ out,
                             const float* __restrict__ scale, const float* __restrict__ shift,
                             int total4, int cmask4) {
    int i = blockIdx.x * blockDim.x + threadIdx.x;
    if (i >= total4) return;
    int c4 = i & cmask4;
    ushort4 v = ((const ushort4*)in)[i];
    float4 sc = ((const float4*)scale)[c4];
    float4 sh = ((const float4*)shift)[c4];
    ((ushort4*)out)[i] = make_ushort4(
        f2bf(fmaxf(bf2f(v.x) * sc.x + sh.x, 0.f)), f2bf(fmaxf(bf2f(v.y) * sc.y + sh.y, 0.f)),
        f2bf(fmaxf(bf2f(v.z) * sc.z + sh.z, 0.f)), f2bf(fmaxf(bf2f(v.w) * sc.w + sh.w, 0.f)));
}

__global__ void k_bn_relu_bf(const u16* __restrict__ in, float* __restrict__ out,
                             const float* __restrict__ scale, const float* __restrict__ shift,
                             int total4, int cmask4) {
    int i = blockIdx.x * blockDim.x + threadIdx.x;
    if (i >= total4) return;
    int c4 = i & cmask4;
    ushort4 v = ((const ushort4*)in)[i];
    float4 sc = ((const float4*)scale)[c4];
    float4 sh = ((const float4*)shift)[c4];
    ((float4*)out)[i] = make_float4(
        fmaxf(bf2f(v.x) * sc.x + sh.x, 0.f), fmaxf(bf2f(v.y) * sc.y + sh.y, 0.f),
        fmaxf(bf2f(v.z) * sc.z + sh.z, 0.f), fmaxf(bf2f(v.w) * sc.w + sh.w, 0.f));
}

// ---------------------------------------------------------------------------
// fused attention: 8 edges/iter, 16-lane groups for score, KV interleaved,
// Q read as bf16 (R4 best-measured variant)
// ---------------------------------------------------------------------------
__global__ void k_attn_aggr(const u16* __restrict__ Qb, const u16* __restrict__ KV,
                            const int* __restrict__ row_ptr, const int2* __restrict__ cv,
                            const float* __restrict__ gate, const float* __restrict__ low,
                            float* __restrict__ high, float* __restrict__ outp, int N) {
    int wid = blockIdx.x * 4 + (threadIdx.x >> 6);
    if (wid >= N) return;
    int lane = threadIdx.x & 63;
    int sub = lane & 15;
    int g = lane >> 4;
    float qs[8];
    {
        short8 q8 = *(const short8*)(Qb + (size_t)wid * HD + sub * 8);
        #pragma unroll
        for (int k = 0; k < 8; ++k) qs[k] = bf2f((u16)q8[k]);
    }
    float2 qv;
    {
        ushort2 qt = *(const ushort2*)(Qb + (size_t)wid * HD + lane * 2);
        qv.x = bf2f(qt.x); qv.y = bf2f(qt.y);
    }
    float n0 = 0, n1 = 0, den = 0;
    int s = row_ptr[wid], e = row_ptr[wid + 1];
    int j = s;
    for (; j + 7 < e; j += 8) {
        int cg0 = cv[j + g].x;
        int cg1 = cv[j + 4 + g].x;
        short8 ka = *(const short8*)(KV + (size_t)cg0 * 256 + sub * 8);
        short8 kb = *(const short8*)(KV + (size_t)cg1 * 256 + sub * 8);
        float p0 = qs[0] * bf2f((u16)ka[0]) + qs[1] * bf2f((u16)ka[1])
                 + qs[2] * bf2f((u16)ka[2]) + qs[3] * bf2f((u16)ka[3])
                 + qs[4] * bf2f((u16)ka[4]) + qs[5] * bf2f((u16)ka[5])
                 + qs[6] * bf2f((u16)ka[6]) + qs[7] * bf2f((u16)ka[7]);
        float p1 = qs[0] * bf2f((u16)kb[0]) + qs[1] * bf2f((u16)kb[1])
                 + qs[2] * bf2f((u16)kb[2]) + qs[3] * bf2f((u16)kb[3])
                 + qs[4] * bf2f((u16)kb[4]) + qs[5] * bf2f((u16)kb[5])
                 + qs[6] * bf2f((u16)kb[6]) + qs[7] * bf2f((u16)kb[7]);
        p0 += __shfl_xor(p0, 1); p1 += __shfl_xor(p1, 1);
        p0 += __shfl_xor(p0, 2); p1 += __shfl_xor(p1, 2);
        p0 += __shfl_xor(p0, 4); p1 += __shfl_xor(p1, 4);
        p0 += __shfl_xor(p0, 8); p1 += __shfl_xor(p1, 8);
        float sc0 = p0 * 0.08838834764831845f;
        float sc1 = p1 * 0.08838834764831845f;
        float ls0 = sc0 > 0.f ? sc0 : 0.2f * sc0;
        float ls1 = sc1 > 0.f ? sc1 : 0.2f * sc1;
        float ex0 = __expf(ls0);
        float ex1 = __expf(ls1);
        float exb[8]; int cb[8];
        #pragma unroll
        for (int t = 0; t < 4; ++t) {
            exb[t]     = __shfl(ex0, t << 4); cb[t]     = __shfl(cg0, t << 4);
            exb[4 + t] = __shfl(ex1, t << 4); cb[4 + t] = __shfl(cg1, t << 4);
        }
        ushort2 vb[8];
        #pragma unroll
        for (int t = 0; t < 8; ++t) vb[t] = *(const ushort2*)(KV + (size_t)cb[t] * 256 + 128 + lane * 2);
        #pragma unroll
        for (int t = 0; t < 8; ++t) {
            n0 += exb[t] * bf2f(vb[t].x);
            n1 += exb[t] * bf2f(vb[t].y);
            den += exb[t];
        }
    }
    for (; j + 3 < e; j += 4) {
        int cg = cv[j + g].x;
        short8 kk = *(const short8*)(KV + (size_t)cg * 256 + sub * 8);
        float p = qs[0] * bf2f((u16)kk[0]) + qs[1] * bf2f((u16)kk[1])
                + qs[2] * bf2f((u16)kk[2]) + qs[3] * bf2f((u16)kk[3])
                + qs[4] * bf2f((u16)kk[4]) + qs[5] * bf2f((u16)kk[5])
                + qs[6] * bf2f((u16)kk[6]) + qs[7] * bf2f((u16)kk[7]);
        p += __shfl_xor(p, 1); p += __shfl_xor(p, 2);
        p += __shfl_xor(p, 4); p += __shfl_xor(p, 8);
        float sc = p * 0.08838834764831845f;
        float ls = sc > 0.f ? sc : 0.2f * sc;
        float ex = __expf(ls);
        float exb[4]; int cb[4];
        #pragma unroll
        for (int t = 0; t < 4; ++t) { exb[t] = __shfl(ex, t << 4); cb[t] = __shfl(cg, t << 4); }
        ushort2 vb[4];
        #pragma unroll
        for (int t = 0; t < 4; ++t) vb[t] = *(const ushort2*)(KV + (size_t)cb[t] * 256 + 128 + lane * 2);
        #pragma unroll
        for (int t = 0; t < 4; ++t) {
            n0 += exb[t] * bf2f(vb[t].x);
            n1 += exb[t] * bf2f(vb[t].y);
            den += exb[t];
        }
    }
    for (; j < e; ++j) {
        int c0 = cv[j].x;
        ushort2 kb0 = *(const ushort2*)(KV + (size_t)c0 * 256 + lane * 2);
        ushort2 vb0 = *(const ushort2*)(KV + (size_t)c0 * 256 + 128 + lane * 2);
        float sc0 = qv.x * bf2f(kb0.x) + qv.y * bf2f(kb0.y);
        #pragma unroll
        for (int off = 32; off > 0; off >>= 1) sc0 += __shfl_xor(sc0, off);
        float p = sc0 * 0.08838834764831845f;
        float ls = p > 0.f ? p : 0.2f * p;
        float ex = __expf(ls);
        n0 += ex * bf2f(vb0.x); n1 += ex * bf2f(vb0.y); den += ex;
    }
    float inv = 1.0f / (den + 1e-16f);
    float h0 = n0 * inv, h1 = n1 * inv;
    *(float2*)(high + (size_t)wid * HD + lane * 2) = make_float2(h0, h1);
    float g0 = gate[(size_t)wid * 2 + 0], g1 = gate[(size_t)wid * 2 + 1];
    float2 lw = *(const float2*)(low + (size_t)wid * HD + lane * 2);
    *(float2*)(outp + (size_t)wid * HD + lane * 2) = make_float2(g0 * lw.x + g1 * h0, g0 * lw.y + g1 * h1);
}

// ---------------------------------------------------------------------------
extern "C" void kernel_launch(void* const* d_in, const int* in_sizes, int n_in,
                              void* d_out, int out_size, void* d_ws, size_t ws_size,
                              hipStream_t stream) {
    const float* x      = (const float*)d_in[0];
    const int*   erow   = (const int*)d_in[1];
    const int*   ecol   = (const int*)d_in[2];
    const float* avals  = (const float*)d_in[3];
    const float* W_gc1  = (const float*)d_in[4];
    const float* bn1_g  = (const float*)d_in[6];
    const float* bn1_b  = (const float*)d_in[7];
    const float* W_gc2  = (const float*)d_in[8];
    const float* bn2_g  = (const float*)d_in[10];
    const float* bn2_b  = (const float*)d_in[11];
    const float* Wg1    = (const float*)d_in[12];
    const float* bg1    = (const float*)d_in[13];
    const float* ln_g   = (const float*)d_in[14];
    const float* ln_b   = (const float*)d_in[15];
    const float* Wg2    = (const float*)d_in[16];
    const float* bg2    = (const float*)d_in[17];
    const float* Wxp    = (const float*)d_in[18];
    const float* bxp    = (const float*)d_in[19];
    const float* rscale = (const float*)d_in[20];
    const float* rn_g   = (const float*)d_in[21];
    const float* rn_b   = (const float*)d_in[22];
    const float* Wq     = (const float*)d_in[23];
    const float* Wk     = (const float*)d_in[24];
    const float* Wv     = (const float*)d_in[25];

    const int N = in_sizes[0] / F0;   // 100000
    const int E = in_sizes[1];        // 3200000

    char* base = (char*)d_ws;
    size_t off = 0;
    auto carve = [&](size_t bytes) -> char* {
        char* p = base + off;
        off += (bytes + 255) & ~(size_t)255;
        return p;
    };
    double* stats  = (double*)carve(4096);
    float* scaleb  = (float*)carve(1024);
    float* shiftb  = (float*)carve(1024);
    int*   partials= (int*)carve(2048);
    u16* Wgc1t = (u16*)carve(65536 * 2);
    u16* Wgc2t = (u16*)carve(32768 * 2);
    u16* Wdt   = (u16*)carve(32768 * 2);
    u16* W1t   = (u16*)carve(32768 * 2);
    u16* W2t   = (u16*)carve(32768 * 2);
    u16* Wxpt  = (u16*)carve(32768 * 2);
    u16* Wqt   = (u16*)carve(16384 * 2);
    u16* Wkt   = (u16*)carve(16384 * 2);
    u16* Wvt   = (u16*)carve(16384 * 2);
    int*   row_ptr = (int*)carve((size_t)(N + 1) * 4);
    int*   cursor  = (int*)carve((size_t)N * 4);   // hist counts
    float* deg     = (float*)carve((size_t)N * 4);
    int2*  cv      = (int2*)carve((size_t)E * 8);        // packed (col, val)
    u16*   x_bf    = (u16*)carve((size_t)NP * F0 * 2);
    u16*   kvb     = (u16*)carve((size_t)NP * 256 * 2);  // KV interleaved [N][256]
    u16*   AX_bf   = (u16*)carve((size_t)NP * F0 * 2);
    u16*   XSTD_bf = (u16*)carve((size_t)NP * F0 * 2);
    u16*   h1_bf   = (u16*)carve((size_t)NP * F0 * 2);   // S1 bf16 -> h1 -> resid
    u16*   S2_bf   = (u16*)carve((size_t)NP * HD * 2);
    u16*   G2_bf   = (u16*)carve((size_t)NP * HD * 2);
    float* M3      = (float*)carve((size_t)NP * HD * 4); // rank -> Qb
    (void)ws_size; (void)n_in; (void)out_size;

    u16*   S1_bf = h1_bf;
    u16*   resid_bf = h1_bf;                       // h1 dead after gc2 GEMM
    int*   rank  = (int*)M3;                       // dead after scatter
    u16*   Qb    = (u16*)M3;                       // live from mm_qkv3 on

    float* out_o    = (float*)d_out;
    float* out_gate = out_o + (size_t)N * HD;
    float* out_low  = out_gate + (size_t)N * 2;
    float* out_high = out_low + (size_t)N * HD;

    const int eb  = (E + 255) / 256;
    const int wb  = (N + 3) / 4;
    const int NB1 = (N + 1023) / 1024;
    const int gx  = (N + 127) / 128;
    const dim3 blk(256);

    // ===== CSR (hist+rank -> scan -> atomic-free scatter) =====
    hipMemsetAsync(cursor, 0, (size_t)N * 4, stream);
    k_hist_rank<<<eb, blk, 0, stream>>>(erow, cursor, rank, E);
    k_scan_blk<<<NB1, 1024, 0, stream>>>(cursor, row_ptr + 1, partials, N);
    k_scan_part<<<1, 128, 0, stream>>>(partials, NB1);
    k_scan_add<<<NB1, 1024, 0, stream>>>(row_ptr, partials, N);
    k_scatter_direct<<<eb, blk, 0, stream>>>(erow, ecol, avals, rank, row_ptr, cv, E);

    // ===== casts =====
    k_cast_x<<<(N * 64 + 255) / 256, blk, 0, stream>>>(x, x_bf, N * 64);
    k_prep_w<<<dim3(256, 1, 9), blk, 0, stream>>>(W_gc1, W_gc2, Wg1, Wxp, Wq, Wk, Wv,
                                                  Wgc1t, Wgc2t, Wdt, W1t, W2t, Wxpt, Wqt, Wkt, Wvt);

    // ===== spmm over x (fused finalize: AX_bf, XSTD_bf, deg directly) =====
    k_spmm_x2<<<wb, blk, 0, stream>>>(x_bf, row_ptr, cv, AX_bf, XSTD_bf, deg, N);

    // ===== low path =====
    k_mm_bf<<<dim3(gx, 2), blk, 0, stream>>>(AX_bf, Wgc1t, S1_bf, N, 256, 256);
    hipMemsetAsync(stats, 0, 4096, stream);
    k_bn_stats_bf<<<1024, blk, 0, stream>>>(S1_bf, stats, N, 256);
    k_bn_fin<<<1, blk, 0, stream>>>(stats, bn1_g, bn1_b, scaleb, shiftb, 256, 1.0 / N);
    k_bn_relu_bb<<<(N * 64 + 255) / 256, blk, 0, stream>>>(S1_bf, h1_bf, scaleb, shiftb, N * 64, 63);
    k_mm_bf<<<dim3(gx, 1), blk, 0, stream>>>(h1_bf, Wgc2t, G2_bf, N, 256, 128);
    k_spmm128<<<wb, blk, 0, stream>>>(G2_bf, row_ptr, cv, S2_bf, N);
    hipMemsetAsync(stats, 0, 2048, stream);
    k_bn_stats_bf<<<1024, blk, 0, stream>>>(S2_bf, stats, N, 128);
    k_bn_fin<<<1, blk, 0, stream>>>(stats, bn2_g, bn2_b, scaleb, shiftb, 128, 1.0 / N);
    k_bn_relu_bf<<<(N * 32 + 255) / 256, blk, 0, stream>>>(S2_bf, out_low, scaleb, shiftb, N * 32, 31);

    // ===== gating (fused GEMM + LN + softmax) =====
    k_mm_gate<<<dim3(gx, 1), blk, 0, stream>>>(x_bf, AX_bf, XSTD_bf, Wdt, W1t, W2t,
                                               bg1, Wg1 + (size_t)768 * 128, deg,
                                               ln_g, ln_b, Wg2, bg2, out_gate, N);

    // ===== high path =====
    k_mm_xp<<<dim3(gx, 1), blk, 0, stream>>>(x_bf, Wxpt, bxp, out_low, rn_g, rn_b, rscale,
                                             resid_bf, N);
    k_mm_qkv3<<<dim3(gx, 1), blk, 0, stream>>>(resid_bf, Wqt, Wkt, Wvt, Qb, kvb, N);
    k_attn_aggr<<<wb, blk, 0, stream>>>(Qb, kvb, row_ptr, cv, out_gate, out_low, out_high, out_o, N);
}

// Round 8
// 1362.415 us; speedup vs baseline: 1.1228x; 1.1228x over previous
//
#include <hip/hip_runtime.h>

#define F0 256
#define HD 128
#define NP 100352   // padded rows (784*128)

typedef unsigned short u16;
typedef __attribute__((ext_vector_type(8))) short short8;
typedef __attribute__((ext_vector_type(4))) float f32x4;

__device__ inline float bf2f(u16 u) {
    union { unsigned int i; float f; } v; v.i = ((unsigned int)u) << 16; return v.f;
}
__device__ inline u16 f2bf(float f) {
    union { float f; unsigned int i; } v; v.f = f;
    unsigned int r = v.i + 0x7FFF + ((v.i >> 16) & 1);
    return (u16)(r >> 16);
}

// 4-level butterfly over the 16-lane group (l&15)
__device__ inline float rsum16(float v) {
    v += __shfl_xor(v, 1); v += __shfl_xor(v, 2);
    v += __shfl_xor(v, 4); v += __shfl_xor(v, 8);
    return v;
}

#define GLOAD16(gp, lp) __builtin_amdgcn_global_load_lds( \
    (const __attribute__((address_space(1))) void*)(gp), \
    (__attribute__((address_space(3))) void*)(lp), 16, 0, 0)

// ---------------------------------------------------------------------------
// CSR build: hist(+rank) -> scan -> atomic-free scatter
// ---------------------------------------------------------------------------
__global__ void k_hist_rank(const int* __restrict__ row, int* __restrict__ counts,
                            int* __restrict__ rank, int E) {
    int e = blockIdx.x * blockDim.x + threadIdx.x;
    if (e < E) rank[e] = atomicAdd(&counts[row[e]], 1);
}

__global__ void k_scan_blk(const int* __restrict__ counts, int* __restrict__ scan_out,
                           int* __restrict__ partials, int n) {
    __shared__ int wsum[16];
    int t = threadIdx.x;
    int i = blockIdx.x * 1024 + t;
    int v = (i < n) ? counts[i] : 0;
    int lane = t & 63, w = t >> 6;
    #pragma unroll
    for (int off = 1; off < 64; off <<= 1) { int u = __shfl_up(v, off); if (lane >= off) v += u; }
    if (lane == 63) wsum[w] = v;
    __syncthreads();
    if (t < 16) {
        int s = wsum[t];
        #pragma unroll
        for (int off = 1; off < 16; off <<= 1) { int u = __shfl_up(s, off); if (t >= off) s += u; }
        wsum[t] = s;
    }
    __syncthreads();
    int add = (w > 0) ? wsum[w - 1] : 0;
    if (i < n) scan_out[i] = v + add;
    if (t == 1023) partials[blockIdx.x] = wsum[15];
}

__global__ void k_scan_part(int* partials, int nb) {
    __shared__ int ws2[2];
    int t = threadIdx.x;
    int v = (t < nb) ? partials[t] : 0;
    int lane = t & 63, w = t >> 6;
    #pragma unroll
    for (int off = 1; off < 64; off <<= 1) { int u = __shfl_up(v, off); if (lane >= off) v += u; }
    if (lane == 63) ws2[w] = v;
    __syncthreads();
    if (w == 1) v += ws2[0];
    if (t < nb) partials[t] = v;
}

__global__ void k_scan_add(int* __restrict__ row_ptr, const int* __restrict__ partials, int n) {
    int b = blockIdx.x;
    int i = b * 1024 + threadIdx.x;
    if (b == 0 && threadIdx.x == 0) row_ptr[0] = 0;
    int add = (b > 0) ? partials[b - 1] : 0;
    if (i < n) row_ptr[1 + i] += add;
}

__global__ void k_scatter_direct(const int* __restrict__ row, const int* __restrict__ ecol,
                                 const float* __restrict__ avals, const int* __restrict__ rank,
                                 const int* __restrict__ row_ptr, int2* __restrict__ cv, int E) {
    int e = blockIdx.x * blockDim.x + threadIdx.x;
    if (e >= E) return;
    int r = row[e];
    int c = __builtin_nontemporal_load(ecol + e);
    float v = __builtin_nontemporal_load(avals + e);
    int rk = __builtin_nontemporal_load(rank + e);
    int pos = row_ptr[r] + rk;
    cv[pos] = make_int2(c, __float_as_int(v));
}

// ---------------------------------------------------------------------------
// casts
// ---------------------------------------------------------------------------
__global__ void k_cast_x(const float* __restrict__ x, u16* __restrict__ xb, int total4) {
    int i = blockIdx.x * blockDim.x + threadIdx.x;
    if (i >= total4) return;
    float4 v = ((const float4*)x)[i];
    ((ushort4*)xb)[i] = make_ushort4(f2bf(v.x), f2bf(v.y), f2bf(v.z), f2bf(v.w));
}

__global__ void k_prep_w(const float* __restrict__ W_gc1, const float* __restrict__ W_gc2,
                         const float* __restrict__ Wg1, const float* __restrict__ Wxp,
                         const float* __restrict__ Wq, const float* __restrict__ Wk,
                         const float* __restrict__ Wv,
                         u16* Wgc1t, u16* Wgc2t, u16* Wdt, u16* W1t, u16* W2t,
                         u16* Wxpt, u16* Wqt, u16* Wkt, u16* Wvt) {
    int z = blockIdx.z;
    int idx = blockIdx.x * 256 + threadIdx.x;
    if (z == 0) { if (idx < 65536) { int n = idx >> 8, k = idx & 255; Wgc1t[idx] = f2bf(W_gc1[k * 256 + n]); } }
    else if (z == 1) { if (idx < 32768) { int n = idx >> 8, k = idx & 255; Wgc2t[idx] = f2bf(W_gc2[k * 128 + n]); } }
    else if (z == 2) { if (idx < 32768) { int n = idx >> 8, k = idx & 255; Wdt[idx] = f2bf(Wg1[k * 128 + n] - Wg1[(k + 256) * 128 + n]); } }
    else if (z == 3) { if (idx < 32768) { int n = idx >> 8, k = idx & 255; W1t[idx] = f2bf(Wg1[(k + 256) * 128 + n]); } }
    else if (z == 4) { if (idx < 32768) { int n = idx >> 8, k = idx & 255; W2t[idx] = f2bf(Wg1[(k + 512) * 128 + n]); } }
    else if (z == 5) { if (idx < 32768) { int n = idx >> 8, k = idx & 255; Wxpt[idx] = f2bf(Wxp[k * 128 + n]); } }
    else if (z == 6) { if (idx < 16384) { int n = idx >> 7, k = idx & 127; Wqt[idx] = f2bf(Wq[k * 128 + n]); } }
    else if (z == 7) { if (idx < 16384) { int n = idx >> 7, k = idx & 127; Wkt[idx] = f2bf(Wk[k * 128 + n]); } }
    else if (z == 8) { if (idx < 16384) { int n = idx >> 7, k = idx & 127; Wvt[idx] = f2bf(Wv[k * 128 + n]); } }
}

// ---------------------------------------------------------------------------
// SpMM over x with fused mean/std finalize (unroll-8)
// ---------------------------------------------------------------------------
__global__ void k_spmm_x2(const u16* __restrict__ Xb, const int* __restrict__ row_ptr,
                          const int2* __restrict__ cv,
                          u16* __restrict__ AXb, u16* __restrict__ XSTDb,
                          float* __restrict__ deg, int N) {
    int wid = blockIdx.x * 4 + (threadIdx.x >> 6);
    if (wid >= N) return;
    int lane = threadIdx.x & 63;
    float a0 = 0, a1 = 0, a2 = 0, a3 = 0;
    float q0 = 0, q1 = 0, q2 = 0, q3 = 0, d = 0;
    int s = row_ptr[wid], e = row_ptr[wid + 1];
    int j = s;
    for (; j + 7 < e; j += 8) {
        int2 cc[8]; ushort4 xb[8];
        #pragma unroll
        for (int t = 0; t < 8; ++t) cc[t] = cv[j + t];
        #pragma unroll
        for (int t = 0; t < 8; ++t) xb[t] = *(const ushort4*)(Xb + (size_t)cc[t].x * F0 + lane * 4);
        #pragma unroll
        for (int t = 0; t < 8; ++t) {
            float x0 = bf2f(xb[t].x), x1 = bf2f(xb[t].y), x2 = bf2f(xb[t].z), x3 = bf2f(xb[t].w);
            float vv = __int_as_float(cc[t].y);
            a0 += vv * x0; a1 += vv * x1; a2 += vv * x2; a3 += vv * x3;
            q0 += vv * x0 * x0; q1 += vv * x1 * x1; q2 += vv * x2 * x2; q3 += vv * x3 * x3;
            d += vv;
        }
    }
    for (; j < e; ++j) {
        int2 cc = cv[j];
        float v0 = __int_as_float(cc.y);
        ushort4 xb0 = *(const ushort4*)(Xb + (size_t)cc.x * F0 + lane * 4);
        float x0 = bf2f(xb0.x), x1 = bf2f(xb0.y), x2 = bf2f(xb0.z), x3 = bf2f(xb0.w);
        a0 += v0 * x0; a1 += v0 * x1; a2 += v0 * x2; a3 += v0 * x3;
        q0 += v0 * x0 * x0; q1 += v0 * x1 * x1; q2 += v0 * x2 * x2; q3 += v0 * x3 * x3;
        d += v0;
    }
    float inv = 1.0f / (d + 1e-8f);
    float m0 = a0 * inv, m1 = a1 * inv, m2 = a2 * inv, m3 = a3 * inv;
    float s0 = sqrtf(fmaxf(q0 * inv - m0 * m0, 0.f));
    float s1 = sqrtf(fmaxf(q1 * inv - m1 * m1, 0.f));
    float s2 = sqrtf(fmaxf(q2 * inv - m2 * m2, 0.f));
    float s3 = sqrtf(fmaxf(q3 * inv - m3 * m3, 0.f));
    *(ushort4*)(AXb + (size_t)wid * F0 + lane * 4) = make_ushort4(f2bf(a0), f2bf(a1), f2bf(a2), f2bf(a3));
    *(ushort4*)(XSTDb + (size_t)wid * F0 + lane * 4) = make_ushort4(f2bf(s0), f2bf(s1), f2bf(s2), f2bf(s3));
    if (lane == 0) deg[wid] = d;
}

// bf16 in, bf16 out (unroll-8)
__global__ void k_spmm128(const u16* __restrict__ Xb, const int* __restrict__ row_ptr,
                          const int2* __restrict__ cv, u16* __restrict__ OUT, int N) {
    int wid = blockIdx.x * 4 + (threadIdx.x >> 6);
    if (wid >= N) return;
    int lane = threadIdx.x & 63;
    float a0 = 0, a1 = 0;
    int s = row_ptr[wid], e = row_ptr[wid + 1];
    int j = s;
    for (; j + 7 < e; j += 8) {
        int2 cc[8]; ushort2 xb[8];
        #pragma unroll
        for (int t = 0; t < 8; ++t) cc[t] = cv[j + t];
        #pragma unroll
        for (int t = 0; t < 8; ++t) xb[t] = *(const ushort2*)(Xb + (size_t)cc[t].x * HD + lane * 2);
        #pragma unroll
        for (int t = 0; t < 8; ++t) {
            float vv = __int_as_float(cc[t].y);
            a0 += vv * bf2f(xb[t].x); a1 += vv * bf2f(xb[t].y);
        }
    }
    for (; j < e; ++j) {
        int2 cc = cv[j];
        float v0 = __int_as_float(cc.y);
        ushort2 x0 = *(const ushort2*)(Xb + (size_t)cc.x * HD + lane * 2);
        a0 += v0 * bf2f(x0.x); a1 += v0 * bf2f(x0.y);
    }
    *(ushort2*)(OUT + (size_t)wid * HD + lane * 2) = make_ushort2(f2bf(a0), f2bf(a1));
}

// ---------------------------------------------------------------------------
// bf16 MFMA GEMM core: C[128,128] tile = A[M,K] @ Bt[N,K]^T, BK=32
// ---------------------------------------------------------------------------
__device__ inline void mm_core(const u16* __restrict__ A, const u16* __restrict__ Bt,
                               int K, int ldA, int ldB, int m0, int n0,
                               u16* As, u16* Bs, f32x4 acc[4][4]) {
    int t = threadIdx.x, w = t >> 6, l = t & 63;
    int wr = (w >> 1) * 64, wc = (w & 1) * 64;
    int aoff = (wr + (l & 15)) * 32 + (l >> 4) * 8;
    int boff = (wc + (l & 15)) * 32 + (l >> 4) * 8;
    for (int k0 = 0; k0 < K; k0 += 32) {
        __syncthreads();
        #pragma unroll
        for (int s = 0; s < 2; ++s) {
            int i = s * 256 + t;
            int row = i >> 2, ch = i & 3;
            GLOAD16(A + (size_t)(m0 + row) * ldA + k0 + ch * 8, As + i * 8);
            GLOAD16(Bt + (size_t)(n0 + row) * ldB + k0 + ch * 8, Bs + i * 8);
        }
        __syncthreads();
        short8 af[4], bfr[4];
        #pragma unroll
        for (int i = 0; i < 4; ++i) af[i] = *(const short8*)(As + aoff + i * 16 * 32);
        #pragma unroll
        for (int j = 0; j < 4; ++j) bfr[j] = *(const short8*)(Bs + boff + j * 16 * 32);
        #pragma unroll
        for (int i = 0; i < 4; ++i)
            #pragma unroll
            for (int j = 0; j < 4; ++j)
                acc[i][j] = __builtin_amdgcn_mfma_f32_16x16x32_bf16(af[i], bfr[j], acc[i][j], 0, 0, 0);
    }
}

__device__ inline void mm_zero(f32x4 acc[4][4]) {
    #pragma unroll
    for (int i = 0; i < 4; ++i)
        #pragma unroll
        for (int j = 0; j < 4; ++j)
            acc[i][j] = (f32x4){0.f, 0.f, 0.f, 0.f};
}

// gc1 GEMM (AX @ Wgc1 -> S1 bf16) with fused per-column BN stats accumulation
__global__ __launch_bounds__(256) void k_mm_gc1(const u16* __restrict__ A, const u16* __restrict__ Bt,
                                                u16* __restrict__ C, double* __restrict__ stats, int M) {
    __shared__ __align__(16) u16 As[128 * 32];
    __shared__ __align__(16) u16 Bs[128 * 32];
    __shared__ float cs1[2][128], cs2[2][128];
    int m0 = blockIdx.x * 128, n0 = blockIdx.y * 128;
    f32x4 acc[4][4]; mm_zero(acc);
    mm_core(A, Bt, 256, 256, 256, m0, n0, As, Bs, acc);
    int t = threadIdx.x, w = t >> 6, l = t & 63;
    int rbase = m0 + (w >> 1) * 64 + (l >> 4) * 4;
    int cbase = n0 + (w & 1) * 64 + (l & 15);
    float sj1[4], sj2[4];
    #pragma unroll
    for (int j = 0; j < 4; ++j) { sj1[j] = 0.f; sj2[j] = 0.f; }
    #pragma unroll
    for (int j = 0; j < 4; ++j)
        #pragma unroll
        for (int i = 0; i < 4; ++i)
            #pragma unroll
            for (int r = 0; r < 4; ++r) {
                int row = rbase + i * 16 + r;
                if (row < M) {
                    float h = acc[i][j][r];
                    C[(size_t)row * 256 + cbase + j * 16] = f2bf(h);
                    sj1[j] += h; sj2[j] += h * h;
                }
            }
    // lanes l, l^16, l^32, l^48 hold the same columns (different rows)
    #pragma unroll
    for (int j = 0; j < 4; ++j) {
        sj1[j] += __shfl_xor(sj1[j], 16); sj1[j] += __shfl_xor(sj1[j], 32);
        sj2[j] += __shfl_xor(sj2[j], 16); sj2[j] += __shfl_xor(sj2[j], 32);
    }
    if (l < 16) {
        #pragma unroll
        for (int j = 0; j < 4; ++j) {
            int col = (w & 1) * 64 + l + j * 16;
            cs1[w >> 1][col] = sj1[j];
            cs2[w >> 1][col] = sj2[j];
        }
    }
    __syncthreads();
    if (t < 128) {
        double s = (double)cs1[0][t] + (double)cs1[1][t];
        atomicAdd(&stats[n0 + t], s);
    } else {
        int c = t - 128;
        double q = (double)cs2[0][c] + (double)cs2[1][c];
        atomicAdd(&stats[256 + n0 + c], q);
    }
}

// gc2 GEMM (h1 @ Wgc2 -> G2 bf16) where A = relu(S1*scale+shift) applied
// during register-staged LDS write (kills the separate bn_relu pass).
// NOTE: Wgc2t layout is [n=128][k=256] -> ldB = 256 (R7 bug was ld=128).
__global__ __launch_bounds__(256) void k_mm_gc2(const u16* __restrict__ A, const u16* __restrict__ Bt,
                                                const float* __restrict__ scale,
                                                const float* __restrict__ shift,
                                                u16* __restrict__ C, int M) {
    __shared__ __align__(16) u16 As[128 * 32];
    __shared__ __align__(16) u16 Bs[128 * 32];
    int m0 = blockIdx.x * 128;
    int t = threadIdx.x, w = t >> 6, l = t & 63;
    int wr = (w >> 1) * 64, wc = (w & 1) * 64;
    int aoff = (wr + (l & 15)) * 32 + (l >> 4) * 8;
    int boff = (wc + (l & 15)) * 32 + (l >> 4) * 8;
    f32x4 acc[4][4]; mm_zero(acc);
    for (int k0 = 0; k0 < 256; k0 += 32) {
        // reg-load + transform A fragments (no LDS access yet)
        short8 av[2];
        #pragma unroll
        for (int s = 0; s < 2; ++s) {
            int i = s * 256 + t;
            int row = i >> 2, ch = i & 3;
            int col = k0 + ch * 8;
            short8 v = *(const short8*)(A + (size_t)(m0 + row) * 256 + col);
            float4 sa = *(const float4*)(scale + col);
            float4 sb = *(const float4*)(scale + col + 4);
            float4 ha = *(const float4*)(shift + col);
            float4 hb = *(const float4*)(shift + col + 4);
            short8 o;
            o[0] = (short)f2bf(fmaxf(bf2f((u16)v[0]) * sa.x + ha.x, 0.f));
            o[1] = (short)f2bf(fmaxf(bf2f((u16)v[1]) * sa.y + ha.y, 0.f));
            o[2] = (short)f2bf(fmaxf(bf2f((u16)v[2]) * sa.z + ha.z, 0.f));
            o[3] = (short)f2bf(fmaxf(bf2f((u16)v[3]) * sa.w + ha.w, 0.f));
            o[4] = (short)f2bf(fmaxf(bf2f((u16)v[4]) * sb.x + hb.x, 0.f));
            o[5] = (short)f2bf(fmaxf(bf2f((u16)v[5]) * sb.y + hb.y, 0.f));
            o[6] = (short)f2bf(fmaxf(bf2f((u16)v[6]) * sb.z + hb.z, 0.f));
            o[7] = (short)f2bf(fmaxf(bf2f((u16)v[7]) * sb.w + hb.w, 0.f));
            av[s] = o;
        }
        __syncthreads();   // previous iteration's LDS reads complete
        #pragma unroll
        for (int s = 0; s < 2; ++s) {
            int i = s * 256 + t;
            *(short8*)(As + i * 8) = av[s];
            int row = i >> 2, ch = i & 3;
            GLOAD16(Bt + (size_t)row * 256 + k0 + ch * 8, Bs + i * 8);
        }
        __syncthreads();
        short8 af[4], bfr[4];
        #pragma unroll
        for (int i = 0; i < 4; ++i) af[i] = *(const short8*)(As + aoff + i * 16 * 32);
        #pragma unroll
        for (int j = 0; j < 4; ++j) bfr[j] = *(const short8*)(Bs + boff + j * 16 * 32);
        #pragma unroll
        for (int i = 0; i < 4; ++i)
            #pragma unroll
            for (int j = 0; j < 4; ++j)
                acc[i][j] = __builtin_amdgcn_mfma_f32_16x16x32_bf16(af[i], bfr[j], acc[i][j], 0, 0, 0);
    }
    int rbase = m0 + (w >> 1) * 64 + (l >> 4) * 4;
    int cbase = (w & 1) * 64 + (l & 15);
    #pragma unroll
    for (int j = 0; j < 4; ++j)
        #pragma unroll
        for (int i = 0; i < 4; ++i)
            #pragma unroll
            for (int r = 0; r < 4; ++r) {
                int row = rbase + i * 16 + r;
                if (row < M) C[(size_t)row * 128 + cbase + j * 16] = f2bf(acc[i][j][r]);
            }
}

// gating GEMM with fused row-LN + relu + Wg2 dot + softmax -> gate[N][2]
__global__ __launch_bounds__(256) void k_mm_gate(const u16* A0, const u16* A1, const u16* A2,
                                                 const u16* B0, const u16* B1, const u16* B2,
                                                 const float* __restrict__ bg1,
                                                 const float* __restrict__ wlast,
                                                 const float* __restrict__ deg,
                                                 const float* __restrict__ ln_g,
                                                 const float* __restrict__ ln_b,
                                                 const float* __restrict__ Wg2,
                                                 const float* __restrict__ bg2,
                                                 float* __restrict__ gate, int M) {
    __shared__ __align__(16) u16 As[128 * 32];
    __shared__ __align__(16) u16 Bs[128 * 32];
    __shared__ float ps1[2][128], ps2[2][128], pt0[2][128], pt1[2][128];
    int m0 = blockIdx.x * 128;
    f32x4 acc[4][4]; mm_zero(acc);
    mm_core(A0, B0, 256, 256, 256, m0, 0, As, Bs, acc);
    mm_core(A1, B1, 256, 256, 256, m0, 0, As, Bs, acc);
    mm_core(A2, B2, 256, 256, 256, m0, 0, As, Bs, acc);
    int t = threadIdx.x, w = t >> 6, l = t & 63;
    int hcol = w & 1;
    int lr0 = (w >> 1) * 64 + (l >> 4) * 4;
    int cbase = hcol * 64 + (l & 15);
    float wl[4], bg[4], lg[4], lb[4], wa[4], wb_[4];
    #pragma unroll
    for (int j = 0; j < 4; ++j) {
        int col = cbase + j * 16;
        wl[j] = wlast[col]; bg[j] = bg1[col];
        lg[j] = ln_g[col];  lb[j] = ln_b[col];
        wa[j] = Wg2[col * 2 + 0]; wb_[j] = Wg2[col * 2 + 1];
    }
    #pragma unroll
    for (int i = 0; i < 4; ++i)
        #pragma unroll
        for (int r = 0; r < 4; ++r) {
            int row = m0 + lr0 + i * 16 + r;
            float dgv = (row < M) ? deg[row] : 0.f;
            float s1 = 0.f, s2 = 0.f;
            #pragma unroll
            for (int j = 0; j < 4; ++j) {
                float h = acc[i][j][r] + bg[j] + dgv * wl[j];
                acc[i][j][r] = h;
                s1 += h; s2 += h * h;
            }
            s1 = rsum16(s1); s2 = rsum16(s2);
            if ((l & 15) == 0) { ps1[hcol][lr0 + i * 16 + r] = s1; ps2[hcol][lr0 + i * 16 + r] = s2; }
        }
    __syncthreads();
    #pragma unroll
    for (int i = 0; i < 4; ++i)
        #pragma unroll
        for (int r = 0; r < 4; ++r) {
            int lr = lr0 + i * 16 + r;
            float s1 = ps1[0][lr] + ps1[1][lr];
            float s2 = ps2[0][lr] + ps2[1][lr];
            float mu = s1 * (1.f / 128.f);
            float var = s2 * (1.f / 128.f) - mu * mu;
            float is = 1.0f / sqrtf(var + 1e-5f);
            float t0 = 0.f, t1 = 0.f;
            #pragma unroll
            for (int j = 0; j < 4; ++j) {
                float y = fmaxf((acc[i][j][r] - mu) * is * lg[j] + lb[j], 0.f);
                t0 += y * wa[j]; t1 += y * wb_[j];
            }
            t0 = rsum16(t0); t1 = rsum16(t1);
            if ((l & 15) == 0) { pt0[hcol][lr] = t0; pt1[hcol][lr] = t1; }
        }
    __syncthreads();
    if (hcol == 0 && (l & 15) == 0) {
        float b20 = bg2[0], b21 = bg2[1];
        #pragma unroll
        for (int i = 0; i < 4; ++i)
            #pragma unroll
            for (int r = 0; r < 4; ++r) {
                int lr = lr0 + i * 16 + r;
                int row = m0 + lr;
                if (row >= M) continue;
                float t0 = (pt0[0][lr] + pt0[1][lr] + b20) * 0.5f;
                float t1 = (pt1[0][lr] + pt1[1][lr] + b21) * 0.5f;
                float m = fmaxf(t0, t1);
                float e0 = __expf(t0 - m), e1 = __expf(t1 - m);
                float inv = 1.0f / (e0 + e1);
                gate[(size_t)row * 2 + 0] = e0 * inv;
                gate[(size_t)row * 2 + 1] = e1 * inv;
            }
    }
}

// x@Wxp+bxp with fused residual-LN -> resid (bf16)
__global__ __launch_bounds__(256) void k_mm_xp(const u16* __restrict__ A, const u16* __restrict__ Bt,
                                               const float* __restrict__ bias,
                                               const float* __restrict__ low,
                                               const float* __restrict__ g,
                                               const float* __restrict__ b,
                                               const float* __restrict__ rs_ptr,
                                               u16* __restrict__ resid, int M) {
    __shared__ __align__(16) u16 As[128 * 32];
    __shared__ __align__(16) u16 Bs[128 * 32];
    __shared__ float ps1[2][128], ps2[2][128];
    int m0 = blockIdx.x * 128;
    f32x4 acc[4][4]; mm_zero(acc);
    mm_core(A, Bt, 256, 256, 256, m0, 0, As, Bs, acc);
    int t = threadIdx.x, w = t >> 6, l = t & 63;
    int hcol = w & 1;
    int lr0 = (w >> 1) * 64 + (l >> 4) * 4;
    int cbase = hcol * 64 + (l & 15);
    float rs = rs_ptr[0];
    float bx[4], lg[4], lb[4];
    #pragma unroll
    for (int j = 0; j < 4; ++j) {
        int col = cbase + j * 16;
        bx[j] = bias[col]; lg[j] = g[col]; lb[j] = b[col];
    }
    #pragma unroll
    for (int i = 0; i < 4; ++i)
        #pragma unroll
        for (int r = 0; r < 4; ++r) {
            int row = m0 + lr0 + i * 16 + r;
            float s1 = 0.f, s2 = 0.f;
            #pragma unroll
            for (int j = 0; j < 4; ++j) {
                float lv = (row < M) ? low[(size_t)row * 128 + cbase + j * 16] : 0.f;
                float h = rs * (acc[i][j][r] + bx[j] - lv);
                acc[i][j][r] = h;
                s1 += h; s2 += h * h;
            }
            s1 = rsum16(s1); s2 = rsum16(s2);
            if ((l & 15) == 0) { ps1[hcol][lr0 + i * 16 + r] = s1; ps2[hcol][lr0 + i * 16 + r] = s2; }
        }
    __syncthreads();
    #pragma unroll
    for (int i = 0; i < 4; ++i)
        #pragma unroll
        for (int r = 0; r < 4; ++r) {
            int lr = lr0 + i * 16 + r;
            int row = m0 + lr;
            float s1 = ps1[0][lr] + ps1[1][lr];
            float s2 = ps2[0][lr] + ps2[1][lr];
            float mu = s1 * (1.f / 128.f);
            float var = s2 * (1.f / 128.f) - mu * mu;
            float is = 1.0f / sqrtf(var + 1e-5f);
            if (row < M) {
                #pragma unroll
                for (int j = 0; j < 4; ++j) {
                    float y = (acc[i][j][r] - mu) * is * lg[j] + lb[j];
                    resid[(size_t)row * 128 + cbase + j * 16] = f2bf(y);
                }
            }
        }
}

// Q -> bf16 Qb; K/V -> bf16 interleaved KV[N][256]  (R4-proven 3-dispatch form)
__global__ __launch_bounds__(256) void k_mm_qkv(const u16* __restrict__ A,
                                                const u16* Wqt, const u16* Wkt, const u16* Wvt,
                                                u16* Qb, u16* KV, int M) {
    __shared__ __align__(16) u16 As[128 * 32];
    __shared__ __align__(16) u16 Bs[128 * 32];
    int z = blockIdx.z;
    const u16* Bt = (z == 0) ? Wqt : (z == 1) ? Wkt : Wvt;
    int m0 = blockIdx.x * 128;
    f32x4 acc[4][4]; mm_zero(acc);
    mm_core(A, Bt, 128, 128, 128, m0, 0, As, Bs, acc);
    int t = threadIdx.x, w = t >> 6, l = t & 63;
    int rbase = m0 + (w >> 1) * 64 + (l >> 4) * 4;
    int cbase = (w & 1) * 64 + (l & 15);
    if (z == 0) {
        #pragma unroll
        for (int j = 0; j < 4; ++j)
            #pragma unroll
            for (int i = 0; i < 4; ++i)
                #pragma unroll
                for (int r = 0; r < 4; ++r) {
                    int row = rbase + i * 16 + r;
                    if (row < M) Qb[(size_t)row * 128 + cbase + j * 16] = f2bf(acc[i][j][r]);
                }
    } else {
        int coff = (z == 1) ? 0 : 128;
        #pragma unroll
        for (int j = 0; j < 4; ++j)
            #pragma unroll
            for (int i = 0; i < 4; ++i)
                #pragma unroll
                for (int r = 0; r < 4; ++r) {
                    int row = rbase + i * 16 + r;
                    if (row < M) KV[(size_t)row * 256 + coff + cbase + j * 16] = f2bf(acc[i][j][r]);
                }
    }
}

// ---------------------------------------------------------------------------
// BatchNorm (bf16 input) — still used for the bn2 chain
// ---------------------------------------------------------------------------
__global__ void k_bn_stats_bf(const u16* __restrict__ H, double* __restrict__ stats, int N, int C) {
    int t = threadIdx.x;
    int rpt = 256 / C;
    int rsub = t / C;
    int col = t - rsub * C;
    double s = 0.0, q = 0.0;
    for (long r = (long)blockIdx.x * rpt + rsub; r < N; r += (long)gridDim.x * rpt) {
        float v = bf2f(H[(size_t)r * C + col]);
        s += v; q += (double)v * v;
    }
    __shared__ double sh_s[256], sh_q[256];
    sh_s[t] = s; sh_q[t] = q;
    __syncthreads();
    if (t < C) {
        for (int k = 1; k < rpt; ++k) { s += sh_s[t + k * C]; q += sh_q[t + k * C]; }
        atomicAdd(&stats[t], s);
        atomicAdd(&stats[C + t], q);
    }
}

__global__ void k_bn_fin(const double* __restrict__ stats, const float* __restrict__ g,
                         const float* __restrict__ b, float* __restrict__ scale,
                         float* __restrict__ shift, int C, double invN) {
    int t = threadIdx.x;
    if (t >= C) return;
    double mean = stats[t] * invN;
    double var = stats[C + t] * invN - mean * mean;
    float sc = (float)((double)g[t] / sqrt(var + 1e-5));
    scale[t] = sc;
    shift[t] = b[t] - (float)mean * sc;
}

__global__ void k_bn_relu_bf(const u16* __restrict__ in, float* __restrict__ out,
                             const float* __restrict__ scale, const float* __restrict__ shift,
                             int total4, int cmask4) {
    int i = blockIdx.x * blockDim.x + threadIdx.x;
    if (i >= total4) return;
    int c4 = i & cmask4;
    ushort4 v = ((const ushort4*)in)[i];
    float4 sc = ((const float4*)scale)[c4];
    float4 sh = ((const float4*)shift)[c4];
    ((float4*)out)[i] = make_float4(
        fmaxf(bf2f(v.x) * sc.x + sh.x, 0.f), fmaxf(bf2f(v.y) * sc.y + sh.y, 0.f),
        fmaxf(bf2f(v.z) * sc.z + sh.z, 0.f), fmaxf(bf2f(v.w) * sc.w + sh.w, 0.f));
}

// ---------------------------------------------------------------------------
// fused attention: 8 edges/iter, 16-lane groups for score, KV interleaved,
// Q read as bf16 (R4 best-measured variant)
// ---------------------------------------------------------------------------
__global__ void k_attn_aggr(const u16* __restrict__ Qb, const u16* __restrict__ KV,
                            const int* __restrict__ row_ptr, const int2* __restrict__ cv,
                            const float* __restrict__ gate, const float* __restrict__ low,
                            float* __restrict__ high, float* __restrict__ outp, int N) {
    int wid = blockIdx.x * 4 + (threadIdx.x >> 6);
    if (wid >= N) return;
    int lane = threadIdx.x & 63;
    int sub = lane & 15;
    int g = lane >> 4;
    float qs[8];
    {
        short8 q8 = *(const short8*)(Qb + (size_t)wid * HD + sub * 8);
        #pragma unroll
        for (int k = 0; k < 8; ++k) qs[k] = bf2f((u16)q8[k]);
    }
    float2 qv;
    {
        ushort2 qt = *(const ushort2*)(Qb + (size_t)wid * HD + lane * 2);
        qv.x = bf2f(qt.x); qv.y = bf2f(qt.y);
    }
    float n0 = 0, n1 = 0, den = 0;
    int s = row_ptr[wid], e = row_ptr[wid + 1];
    int j = s;
    for (; j + 7 < e; j += 8) {
        int cg0 = cv[j + g].x;
        int cg1 = cv[j + 4 + g].x;
        short8 ka = *(const short8*)(KV + (size_t)cg0 * 256 + sub * 8);
        short8 kb = *(const short8*)(KV + (size_t)cg1 * 256 + sub * 8);
        float p0 = qs[0] * bf2f((u16)ka[0]) + qs[1] * bf2f((u16)ka[1])
                 + qs[2] * bf2f((u16)ka[2]) + qs[3] * bf2f((u16)ka[3])
                 + qs[4] * bf2f((u16)ka[4]) + qs[5] * bf2f((u16)ka[5])
                 + qs[6] * bf2f((u16)ka[6]) + qs[7] * bf2f((u16)ka[7]);
        float p1 = qs[0] * bf2f((u16)kb[0]) + qs[1] * bf2f((u16)kb[1])
                 + qs[2] * bf2f((u16)kb[2]) + qs[3] * bf2f((u16)kb[3])
                 + qs[4] * bf2f((u16)kb[4]) + qs[5] * bf2f((u16)kb[5])
                 + qs[6] * bf2f((u16)kb[6]) + qs[7] * bf2f((u16)kb[7]);
        p0 += __shfl_xor(p0, 1); p1 += __shfl_xor(p1, 1);
        p0 += __shfl_xor(p0, 2); p1 += __shfl_xor(p1, 2);
        p0 += __shfl_xor(p0, 4); p1 += __shfl_xor(p1, 4);
        p0 += __shfl_xor(p0, 8); p1 += __shfl_xor(p1, 8);
        float sc0 = p0 * 0.08838834764831845f;
        float sc1 = p1 * 0.08838834764831845f;
        float ls0 = sc0 > 0.f ? sc0 : 0.2f * sc0;
        float ls1 = sc1 > 0.f ? sc1 : 0.2f * sc1;
        float ex0 = __expf(ls0);
        float ex1 = __expf(ls1);
        float exb[8]; int cb[8];
        #pragma unroll
        for (int t = 0; t < 4; ++t) {
            exb[t]     = __shfl(ex0, t << 4); cb[t]     = __shfl(cg0, t << 4);
            exb[4 + t] = __shfl(ex1, t << 4); cb[4 + t] = __shfl(cg1, t << 4);
        }
        ushort2 vb[8];
        #pragma unroll
        for (int t = 0; t < 8; ++t) vb[t] = *(const ushort2*)(KV + (size_t)cb[t] * 256 + 128 + lane * 2);
        #pragma unroll
        for (int t = 0; t < 8; ++t) {
            n0 += exb[t] * bf2f(vb[t].x);
            n1 += exb[t] * bf2f(vb[t].y);
            den += exb[t];
        }
    }
    for (; j + 3 < e; j += 4) {
        int cg = cv[j + g].x;
        short8 kk = *(const short8*)(KV + (size_t)cg * 256 + sub * 8);
        float p = qs[0] * bf2f((u16)kk[0]) + qs[1] * bf2f((u16)kk[1])
                + qs[2] * bf2f((u16)kk[2]) + qs[3] * bf2f((u16)kk[3])
                + qs[4] * bf2f((u16)kk[4]) + qs[5] * bf2f((u16)kk[5])
                + qs[6] * bf2f((u16)kk[6]) + qs[7] * bf2f((u16)kk[7]);
        p += __shfl_xor(p, 1); p += __shfl_xor(p, 2);
        p += __shfl_xor(p, 4); p += __shfl_xor(p, 8);
        float sc = p * 0.08838834764831845f;
        float ls = sc > 0.f ? sc : 0.2f * sc;
        float ex = __expf(ls);
        float exb[4]; int cb[4];
        #pragma unroll
        for (int t = 0; t < 4; ++t) { exb[t] = __shfl(ex, t << 4); cb[t] = __shfl(cg, t << 4); }
        ushort2 vb[4];
        #pragma unroll
        for (int t = 0; t < 4; ++t) vb[t] = *(const ushort2*)(KV + (size_t)cb[t] * 256 + 128 + lane * 2);
        #pragma unroll
        for (int t = 0; t < 4; ++t) {
            n0 += exb[t] * bf2f(vb[t].x);
            n1 += exb[t] * bf2f(vb[t].y);
            den += exb[t];
        }
    }
    for (; j < e; ++j) {
        int c0 = cv[j].x;
        ushort2 kb0 = *(const ushort2*)(KV + (size_t)c0 * 256 + lane * 2);
        ushort2 vb0 = *(const ushort2*)(KV + (size_t)c0 * 256 + 128 + lane * 2);
        float sc0 = qv.x * bf2f(kb0.x) + qv.y * bf2f(kb0.y);
        #pragma unroll
        for (int off = 32; off > 0; off >>= 1) sc0 += __shfl_xor(sc0, off);
        float p = sc0 * 0.08838834764831845f;
        float ls = p > 0.f ? p : 0.2f * p;
        float ex = __expf(ls);
        n0 += ex * bf2f(vb0.x); n1 += ex * bf2f(vb0.y); den += ex;
    }
    float inv = 1.0f / (den + 1e-16f);
    float h0 = n0 * inv, h1 = n1 * inv;
    *(float2*)(high + (size_t)wid * HD + lane * 2) = make_float2(h0, h1);
    float g0 = gate[(size_t)wid * 2 + 0], g1 = gate[(size_t)wid * 2 + 1];
    float2 lw = *(const float2*)(low + (size_t)wid * HD + lane * 2);
    *(float2*)(outp + (size_t)wid * HD + lane * 2) = make_float2(g0 * lw.x + g1 * h0, g0 * lw.y + g1 * h1);
}

// ---------------------------------------------------------------------------
extern "C" void kernel_launch(void* const* d_in, const int* in_sizes, int n_in,
                              void* d_out, int out_size, void* d_ws, size_t ws_size,
                              hipStream_t stream) {
    const float* x      = (const float*)d_in[0];
    const int*   erow   = (const int*)d_in[1];
    const int*   ecol   = (const int*)d_in[2];
    const float* avals  = (const float*)d_in[3];
    const float* W_gc1  = (const float*)d_in[4];
    const float* bn1_g  = (const float*)d_in[6];
    const float* bn1_b  = (const float*)d_in[7];
    const float* W_gc2  = (const float*)d_in[8];
    const float* bn2_g  = (const float*)d_in[10];
    const float* bn2_b  = (const float*)d_in[11];
    const float* Wg1    = (const float*)d_in[12];
    const float* bg1    = (const float*)d_in[13];
    const float* ln_g   = (const float*)d_in[14];
    const float* ln_b   = (const float*)d_in[15];
    const float* Wg2    = (const float*)d_in[16];
    const float* bg2    = (const float*)d_in[17];
    const float* Wxp    = (const float*)d_in[18];
    const float* bxp    = (const float*)d_in[19];
    const float* rscale = (const float*)d_in[20];
    const float* rn_g   = (const float*)d_in[21];
    const float* rn_b   = (const float*)d_in[22];
    const float* Wq     = (const float*)d_in[23];
    const float* Wk     = (const float*)d_in[24];
    const float* Wv     = (const float*)d_in[25];

    const int N = in_sizes[0] / F0;   // 100000
    const int E = in_sizes[1];        // 3200000

    char* base = (char*)d_ws;
    size_t off = 0;
    auto carve = [&](size_t bytes) -> char* {
        char* p = base + off;
        off += (bytes + 255) & ~(size_t)255;
        return p;
    };
    double* stats  = (double*)carve(4096);
    float* scaleb  = (float*)carve(1024);
    float* shiftb  = (float*)carve(1024);
    int*   partials= (int*)carve(2048);
    u16* Wgc1t = (u16*)carve(65536 * 2);
    u16* Wgc2t = (u16*)carve(32768 * 2);
    u16* Wdt   = (u16*)carve(32768 * 2);
    u16* W1t   = (u16*)carve(32768 * 2);
    u16* W2t   = (u16*)carve(32768 * 2);
    u16* Wxpt  = (u16*)carve(32768 * 2);
    u16* Wqt   = (u16*)carve(16384 * 2);
    u16* Wkt   = (u16*)carve(16384 * 2);
    u16* Wvt   = (u16*)carve(16384 * 2);
    int*   row_ptr = (int*)carve((size_t)(N + 1) * 4);
    int*   cursor  = (int*)carve((size_t)N * 4);   // hist counts
    float* deg     = (float*)carve((size_t)N * 4);
    int2*  cv      = (int2*)carve((size_t)E * 8);        // packed (col, val)
    u16*   x_bf    = (u16*)carve((size_t)NP * F0 * 2);
    u16*   kvb     = (u16*)carve((size_t)NP * 256 * 2);  // KV interleaved [N][256]
    u16*   AX_bf   = (u16*)carve((size_t)NP * F0 * 2);
    u16*   XSTD_bf = (u16*)carve((size_t)NP * F0 * 2);
    u16*   h1_bf   = (u16*)carve((size_t)NP * F0 * 2);   // S1 bf16 -> resid
    u16*   S2_bf   = (u16*)carve((size_t)NP * HD * 2);
    u16*   G2_bf   = (u16*)carve((size_t)NP * HD * 2);
    float* M3      = (float*)carve((size_t)NP * HD * 4); // rank -> Qb
    (void)ws_size; (void)n_in; (void)out_size;

    u16*   S1_bf = h1_bf;
    u16*   resid_bf = h1_bf;                       // S1 dead after gc2 GEMM
    int*   rank  = (int*)M3;                       // dead after scatter
    u16*   Qb    = (u16*)M3;                       // live from mm_qkv on

    float* out_o    = (float*)d_out;
    float* out_gate = out_o + (size_t)N * HD;
    float* out_low  = out_gate + (size_t)N * 2;
    float* out_high = out_low + (size_t)N * HD;

    const int eb  = (E + 255) / 256;
    const int wb  = (N + 3) / 4;
    const int NB1 = (N + 1023) / 1024;
    const int gx  = (N + 127) / 128;
    const dim3 blk(256);

    // ===== CSR (hist+rank -> scan -> atomic-free scatter) =====
    hipMemsetAsync(cursor, 0, (size_t)N * 4, stream);
    k_hist_rank<<<eb, blk, 0, stream>>>(erow, cursor, rank, E);
    k_scan_blk<<<NB1, 1024, 0, stream>>>(cursor, row_ptr + 1, partials, N);
    k_scan_part<<<1, 128, 0, stream>>>(partials, NB1);
    k_scan_add<<<NB1, 1024, 0, stream>>>(row_ptr, partials, N);
    k_scatter_direct<<<eb, blk, 0, stream>>>(erow, ecol, avals, rank, row_ptr, cv, E);

    // ===== casts =====
    k_cast_x<<<(N * 64 + 255) / 256, blk, 0, stream>>>(x, x_bf, N * 64);
    k_prep_w<<<dim3(256, 1, 9), blk, 0, stream>>>(W_gc1, W_gc2, Wg1, Wxp, Wq, Wk, Wv,
                                                  Wgc1t, Wgc2t, Wdt, W1t, W2t, Wxpt, Wqt, Wkt, Wvt);

    // ===== spmm over x (fused finalize: AX_bf, XSTD_bf, deg directly) =====
    k_spmm_x2<<<wb, blk, 0, stream>>>(x_bf, row_ptr, cv, AX_bf, XSTD_bf, deg, N);

    // ===== low path (bn1 stats fused in gc1; bn1 apply fused in gc2 staging) =====
    hipMemsetAsync(stats, 0, 4096, stream);
    k_mm_gc1<<<dim3(gx, 2), blk, 0, stream>>>(AX_bf, Wgc1t, S1_bf, stats, N);
    k_bn_fin<<<1, blk, 0, stream>>>(stats, bn1_g, bn1_b, scaleb, shiftb, 256, 1.0 / N);
    k_mm_gc2<<<dim3(gx, 1), blk, 0, stream>>>(S1_bf, Wgc2t, scaleb, shiftb, G2_bf, N);
    k_spmm128<<<wb, blk, 0, stream>>>(G2_bf, row_ptr, cv, S2_bf, N);
    hipMemsetAsync(stats, 0, 2048, stream);
    k_bn_stats_bf<<<1024, blk, 0, stream>>>(S2_bf, stats, N, 128);
    k_bn_fin<<<1, blk, 0, stream>>>(stats, bn2_g, bn2_b, scaleb, shiftb, 128, 1.0 / N);
    k_bn_relu_bf<<<(N * 32 + 255) / 256, blk, 0, stream>>>(S2_bf, out_low, scaleb, shiftb, N * 32, 31);

    // ===== gating (fused GEMM + LN + softmax) =====
    k_mm_gate<<<dim3(gx, 1), blk, 0, stream>>>(x_bf, AX_bf, XSTD_bf, Wdt, W1t, W2t,
                                               bg1, Wg1 + (size_t)768 * 128, deg,
                                               ln_g, ln_b, Wg2, bg2, out_gate, N);

    // ===== high path =====
    k_mm_xp<<<dim3(gx, 1), blk, 0, stream>>>(x_bf, Wxpt, bxp, out_low, rn_g, rn_b, rscale,
                                             resid_bf, N);
    k_mm_qkv<<<dim3(gx, 1, 3), blk, 0, stream>>>(resid_bf, Wqt, Wkt, Wvt, Qb, kvb, N);
    k_attn_aggr<<<wb, blk, 0, stream>>>(Qb, kvb, row_ptr, cv, out_gate, out_low, out_high, out_o, N);
}

// Round 9
// 1358.541 us; speedup vs baseline: 1.1260x; 1.0029x over previous
//
#include <hip/hip_runtime.h>

#define F0 256
#define HD 128
#define NP 100352   // padded rows (784*128)

typedef unsigned short u16;
typedef __attribute__((ext_vector_type(8))) short short8;
typedef __attribute__((ext_vector_type(4))) float f32x4;
typedef __attribute__((ext_vector_type(2))) float f32x2;

__device__ inline float bf2f(u16 u) {
    union { unsigned int i; float f; } v; v.i = ((unsigned int)u) << 16; return v.f;
}
__device__ inline u16 f2bf(float f) {
    union { float f; unsigned int i; } v; v.f = f;
    unsigned int r = v.i + 0x7FFF + ((v.i >> 16) & 1);
    return (u16)(r >> 16);
}

// 4-level butterfly over the 16-lane group (l&15)
__device__ inline float rsum16(float v) {
    v += __shfl_xor(v, 1); v += __shfl_xor(v, 2);
    v += __shfl_xor(v, 4); v += __shfl_xor(v, 8);
    return v;
}

#define GLOAD16(gp, lp) __builtin_amdgcn_global_load_lds( \
    (const __attribute__((address_space(1))) void*)(gp), \
    (__attribute__((address_space(3))) void*)(lp), 16, 0, 0)

// ---------------------------------------------------------------------------
// CSR build: hist(+rank) -> scan -> atomic-free scatter
// ---------------------------------------------------------------------------
__global__ void k_hist_rank(const int* __restrict__ row, int* __restrict__ counts,
                            int* __restrict__ rank, int E) {
    int e = blockIdx.x * blockDim.x + threadIdx.x;
    if (e < E) rank[e] = atomicAdd(&counts[row[e]], 1);
}

__global__ void k_scan_blk(const int* __restrict__ counts, int* __restrict__ scan_out,
                           int* __restrict__ partials, int n) {
    __shared__ int wsum[16];
    int t = threadIdx.x;
    int i = blockIdx.x * 1024 + t;
    int v = (i < n) ? counts[i] : 0;
    int lane = t & 63, w = t >> 6;
    #pragma unroll
    for (int off = 1; off < 64; off <<= 1) { int u = __shfl_up(v, off); if (lane >= off) v += u; }
    if (lane == 63) wsum[w] = v;
    __syncthreads();
    if (t < 16) {
        int s = wsum[t];
        #pragma unroll
        for (int off = 1; off < 16; off <<= 1) { int u = __shfl_up(s, off); if (t >= off) s += u; }
        wsum[t] = s;
    }
    __syncthreads();
    int add = (w > 0) ? wsum[w - 1] : 0;
    if (i < n) scan_out[i] = v + add;
    if (t == 1023) partials[blockIdx.x] = wsum[15];
}

__global__ void k_scan_part(int* partials, int nb) {
    __shared__ int ws2[2];
    int t = threadIdx.x;
    int v = (t < nb) ? partials[t] : 0;
    int lane = t & 63, w = t >> 6;
    #pragma unroll
    for (int off = 1; off < 64; off <<= 1) { int u = __shfl_up(v, off); if (lane >= off) v += u; }
    if (lane == 63) ws2[w] = v;
    __syncthreads();
    if (w == 1) v += ws2[0];
    if (t < nb) partials[t] = v;
}

__global__ void k_scan_add(int* __restrict__ row_ptr, const int* __restrict__ partials, int n) {
    int b = blockIdx.x;
    int i = b * 1024 + threadIdx.x;
    if (b == 0 && threadIdx.x == 0) row_ptr[0] = 0;
    int add = (b > 0) ? partials[b - 1] : 0;
    if (i < n) row_ptr[1 + i] += add;
}

__global__ void k_scatter_direct(const int* __restrict__ row, const int* __restrict__ ecol,
                                 const float* __restrict__ avals, const int* __restrict__ rank,
                                 const int* __restrict__ row_ptr, int2* __restrict__ cv, int E) {
    int e = blockIdx.x * blockDim.x + threadIdx.x;
    if (e >= E) return;
    int r = row[e];
    int c = __builtin_nontemporal_load(ecol + e);
    float v = __builtin_nontemporal_load(avals + e);
    int rk = __builtin_nontemporal_load(rank + e);
    int pos = row_ptr[r] + rk;
    cv[pos] = make_int2(c, __float_as_int(v));
}

// ---------------------------------------------------------------------------
// casts
// ---------------------------------------------------------------------------
__global__ void k_cast_x(const float* __restrict__ x, u16* __restrict__ xb, int total4) {
    int i = blockIdx.x * blockDim.x + threadIdx.x;
    if (i >= total4) return;
    float4 v = ((const float4*)x)[i];
    ((ushort4*)xb)[i] = make_ushort4(f2bf(v.x), f2bf(v.y), f2bf(v.z), f2bf(v.w));
}

__global__ void k_prep_w(const float* __restrict__ W_gc1, const float* __restrict__ W_gc2,
                         const float* __restrict__ Wg1, const float* __restrict__ Wxp,
                         const float* __restrict__ Wq, const float* __restrict__ Wk,
                         const float* __restrict__ Wv,
                         u16* Wgc1t, u16* Wgc2t, u16* Wdt, u16* W1t, u16* W2t,
                         u16* Wxpt, u16* Wqt, u16* Wkt, u16* Wvt) {
    int z = blockIdx.z;
    int idx = blockIdx.x * 256 + threadIdx.x;
    if (z == 0) { if (idx < 65536) { int n = idx >> 8, k = idx & 255; Wgc1t[idx] = f2bf(W_gc1[k * 256 + n]); } }
    else if (z == 1) { if (idx < 32768) { int n = idx >> 8, k = idx & 255; Wgc2t[idx] = f2bf(W_gc2[k * 128 + n]); } }
    else if (z == 2) { if (idx < 32768) { int n = idx >> 8, k = idx & 255; Wdt[idx] = f2bf(Wg1[k * 128 + n] - Wg1[(k + 256) * 128 + n]); } }
    else if (z == 3) { if (idx < 32768) { int n = idx >> 8, k = idx & 255; W1t[idx] = f2bf(Wg1[(k + 256) * 128 + n]); } }
    else if (z == 4) { if (idx < 32768) { int n = idx >> 8, k = idx & 255; W2t[idx] = f2bf(Wg1[(k + 512) * 128 + n]); } }
    else if (z == 5) { if (idx < 32768) { int n = idx >> 8, k = idx & 255; Wxpt[idx] = f2bf(Wxp[k * 128 + n]); } }
    else if (z == 6) { if (idx < 16384) { int n = idx >> 7, k = idx & 127; Wqt[idx] = f2bf(Wq[k * 128 + n]); } }
    else if (z == 7) { if (idx < 16384) { int n = idx >> 7, k = idx & 127; Wkt[idx] = f2bf(Wk[k * 128 + n]); } }
    else if (z == 8) { if (idx < 16384) { int n = idx >> 7, k = idx & 127; Wvt[idx] = f2bf(Wv[k * 128 + n]); } }
}

// ---------------------------------------------------------------------------
// SpMM over x with fused mean/std finalize (unroll-8)
// ---------------------------------------------------------------------------
__global__ void k_spmm_x2(const u16* __restrict__ Xb, const int* __restrict__ row_ptr,
                          const int2* __restrict__ cv,
                          u16* __restrict__ AXb, u16* __restrict__ XSTDb,
                          float* __restrict__ deg, int N) {
    int wid = blockIdx.x * 4 + (threadIdx.x >> 6);
    if (wid >= N) return;
    int lane = threadIdx.x & 63;
    float a0 = 0, a1 = 0, a2 = 0, a3 = 0;
    float q0 = 0, q1 = 0, q2 = 0, q3 = 0, d = 0;
    int s = row_ptr[wid], e = row_ptr[wid + 1];
    int j = s;
    for (; j + 7 < e; j += 8) {
        int2 cc[8]; ushort4 xb[8];
        #pragma unroll
        for (int t = 0; t < 8; ++t) cc[t] = cv[j + t];
        #pragma unroll
        for (int t = 0; t < 8; ++t) xb[t] = *(const ushort4*)(Xb + (size_t)cc[t].x * F0 + lane * 4);
        #pragma unroll
        for (int t = 0; t < 8; ++t) {
            float x0 = bf2f(xb[t].x), x1 = bf2f(xb[t].y), x2 = bf2f(xb[t].z), x3 = bf2f(xb[t].w);
            float vv = __int_as_float(cc[t].y);
            a0 += vv * x0; a1 += vv * x1; a2 += vv * x2; a3 += vv * x3;
            q0 += vv * x0 * x0; q1 += vv * x1 * x1; q2 += vv * x2 * x2; q3 += vv * x3 * x3;
            d += vv;
        }
    }
    for (; j < e; ++j) {
        int2 cc = cv[j];
        float v0 = __int_as_float(cc.y);
        ushort4 xb0 = *(const ushort4*)(Xb + (size_t)cc.x * F0 + lane * 4);
        float x0 = bf2f(xb0.x), x1 = bf2f(xb0.y), x2 = bf2f(xb0.z), x3 = bf2f(xb0.w);
        a0 += v0 * x0; a1 += v0 * x1; a2 += v0 * x2; a3 += v0 * x3;
        q0 += v0 * x0 * x0; q1 += v0 * x1 * x1; q2 += v0 * x2 * x2; q3 += v0 * x3 * x3;
        d += v0;
    }
    float inv = 1.0f / (d + 1e-8f);
    float m0 = a0 * inv, m1 = a1 * inv, m2 = a2 * inv, m3 = a3 * inv;
    float s0 = sqrtf(fmaxf(q0 * inv - m0 * m0, 0.f));
    float s1 = sqrtf(fmaxf(q1 * inv - m1 * m1, 0.f));
    float s2 = sqrtf(fmaxf(q2 * inv - m2 * m2, 0.f));
    float s3 = sqrtf(fmaxf(q3 * inv - m3 * m3, 0.f));
    *(ushort4*)(AXb + (size_t)wid * F0 + lane * 4) = make_ushort4(f2bf(a0), f2bf(a1), f2bf(a2), f2bf(a3));
    *(ushort4*)(XSTDb + (size_t)wid * F0 + lane * 4) = make_ushort4(f2bf(s0), f2bf(s1), f2bf(s2), f2bf(s3));
    if (lane == 0) deg[wid] = d;
}

// bf16 in, bf16 out (unroll-8)
__global__ void k_spmm128(const u16* __restrict__ Xb, const int* __restrict__ row_ptr,
                          const int2* __restrict__ cv, u16* __restrict__ OUT, int N) {
    int wid = blockIdx.x * 4 + (threadIdx.x >> 6);
    if (wid >= N) return;
    int lane = threadIdx.x & 63;
    float a0 = 0, a1 = 0;
    int s = row_ptr[wid], e = row_ptr[wid + 1];
    int j = s;
    for (; j + 7 < e; j += 8) {
        int2 cc[8]; ushort2 xb[8];
        #pragma unroll
        for (int t = 0; t < 8; ++t) cc[t] = cv[j + t];
        #pragma unroll
        for (int t = 0; t < 8; ++t) xb[t] = *(const ushort2*)(Xb + (size_t)cc[t].x * HD + lane * 2);
        #pragma unroll
        for (int t = 0; t < 8; ++t) {
            float vv = __int_as_float(cc[t].y);
            a0 += vv * bf2f(xb[t].x); a1 += vv * bf2f(xb[t].y);
        }
    }
    for (; j < e; ++j) {
        int2 cc = cv[j];
        float v0 = __int_as_float(cc.y);
        ushort2 x0 = *(const ushort2*)(Xb + (size_t)cc.x * HD + lane * 2);
        a0 += v0 * bf2f(x0.x); a1 += v0 * bf2f(x0.y);
    }
    *(ushort2*)(OUT + (size_t)wid * HD + lane * 2) = make_ushort2(f2bf(a0), f2bf(a1));
}

// ---------------------------------------------------------------------------
// bf16 MFMA GEMM core: C[128,128] tile = A[M,K] @ Bt[N,K]^T, BK=32
// ---------------------------------------------------------------------------
__device__ inline void mm_core(const u16* __restrict__ A, const u16* __restrict__ Bt,
                               int K, int ldA, int ldB, int m0, int n0,
                               u16* As, u16* Bs, f32x4 acc[4][4]) {
    int t = threadIdx.x, w = t >> 6, l = t & 63;
    int wr = (w >> 1) * 64, wc = (w & 1) * 64;
    int aoff = (wr + (l & 15)) * 32 + (l >> 4) * 8;
    int boff = (wc + (l & 15)) * 32 + (l >> 4) * 8;
    for (int k0 = 0; k0 < K; k0 += 32) {
        __syncthreads();
        #pragma unroll
        for (int s = 0; s < 2; ++s) {
            int i = s * 256 + t;
            int row = i >> 2, ch = i & 3;
            GLOAD16(A + (size_t)(m0 + row) * ldA + k0 + ch * 8, As + i * 8);
            GLOAD16(Bt + (size_t)(n0 + row) * ldB + k0 + ch * 8, Bs + i * 8);
        }
        __syncthreads();
        short8 af[4], bfr[4];
        #pragma unroll
        for (int i = 0; i < 4; ++i) af[i] = *(const short8*)(As + aoff + i * 16 * 32);
        #pragma unroll
        for (int j = 0; j < 4; ++j) bfr[j] = *(const short8*)(Bs + boff + j * 16 * 32);
        #pragma unroll
        for (int i = 0; i < 4; ++i)
            #pragma unroll
            for (int j = 0; j < 4; ++j)
                acc[i][j] = __builtin_amdgcn_mfma_f32_16x16x32_bf16(af[i], bfr[j], acc[i][j], 0, 0, 0);
    }
}

__device__ inline void mm_zero(f32x4 acc[4][4]) {
    #pragma unroll
    for (int i = 0; i < 4; ++i)
        #pragma unroll
        for (int j = 0; j < 4; ++j)
            acc[i][j] = (f32x4){0.f, 0.f, 0.f, 0.f};
}

// gc1 GEMM (AX @ Wgc1 -> S1 bf16) with fused per-column BN stats accumulation
__global__ __launch_bounds__(256) void k_mm_gc1(const u16* __restrict__ A, const u16* __restrict__ Bt,
                                                u16* __restrict__ C, double* __restrict__ stats, int M) {
    __shared__ __align__(16) u16 As[128 * 32];
    __shared__ __align__(16) u16 Bs[128 * 32];
    __shared__ float cs1[2][128], cs2[2][128];
    int m0 = blockIdx.x * 128, n0 = blockIdx.y * 128;
    f32x4 acc[4][4]; mm_zero(acc);
    mm_core(A, Bt, 256, 256, 256, m0, n0, As, Bs, acc);
    int t = threadIdx.x, w = t >> 6, l = t & 63;
    int rbase = m0 + (w >> 1) * 64 + (l >> 4) * 4;
    int cbase = n0 + (w & 1) * 64 + (l & 15);
    float sj1[4], sj2[4];
    #pragma unroll
    for (int j = 0; j < 4; ++j) { sj1[j] = 0.f; sj2[j] = 0.f; }
    #pragma unroll
    for (int j = 0; j < 4; ++j)
        #pragma unroll
        for (int i = 0; i < 4; ++i)
            #pragma unroll
            for (int r = 0; r < 4; ++r) {
                int row = rbase + i * 16 + r;
                if (row < M) {
                    float h = acc[i][j][r];
                    C[(size_t)row * 256 + cbase + j * 16] = f2bf(h);
                    sj1[j] += h; sj2[j] += h * h;
                }
            }
    // lanes l, l^16, l^32, l^48 hold the same columns (different rows)
    #pragma unroll
    for (int j = 0; j < 4; ++j) {
        sj1[j] += __shfl_xor(sj1[j], 16); sj1[j] += __shfl_xor(sj1[j], 32);
        sj2[j] += __shfl_xor(sj2[j], 16); sj2[j] += __shfl_xor(sj2[j], 32);
    }
    if (l < 16) {
        #pragma unroll
        for (int j = 0; j < 4; ++j) {
            int col = (w & 1) * 64 + l + j * 16;
            cs1[w >> 1][col] = sj1[j];
            cs2[w >> 1][col] = sj2[j];
        }
    }
    __syncthreads();
    if (t < 128) {
        double s = (double)cs1[0][t] + (double)cs1[1][t];
        atomicAdd(&stats[n0 + t], s);
    } else {
        int c = t - 128;
        double q = (double)cs2[0][c] + (double)cs2[1][c];
        atomicAdd(&stats[256 + n0 + c], q);
    }
}

// gc2 GEMM (h1 @ Wgc2 -> G2 bf16) where A = relu(S1*scale+shift) applied
// during register-staged LDS write. Wgc2t layout [n=128][k=256] -> ldB = 256.
__global__ __launch_bounds__(256) void k_mm_gc2(const u16* __restrict__ A, const u16* __restrict__ Bt,
                                                const float* __restrict__ scale,
                                                const float* __restrict__ shift,
                                                u16* __restrict__ C, int M) {
    __shared__ __align__(16) u16 As[128 * 32];
    __shared__ __align__(16) u16 Bs[128 * 32];
    int m0 = blockIdx.x * 128;
    int t = threadIdx.x, w = t >> 6, l = t & 63;
    int wr = (w >> 1) * 64, wc = (w & 1) * 64;
    int aoff = (wr + (l & 15)) * 32 + (l >> 4) * 8;
    int boff = (wc + (l & 15)) * 32 + (l >> 4) * 8;
    f32x4 acc[4][4]; mm_zero(acc);
    for (int k0 = 0; k0 < 256; k0 += 32) {
        short8 av[2];
        #pragma unroll
        for (int s = 0; s < 2; ++s) {
            int i = s * 256 + t;
            int row = i >> 2, ch = i & 3;
            int col = k0 + ch * 8;
            short8 v = *(const short8*)(A + (size_t)(m0 + row) * 256 + col);
            float4 sa = *(const float4*)(scale + col);
            float4 sb = *(const float4*)(scale + col + 4);
            float4 ha = *(const float4*)(shift + col);
            float4 hb = *(const float4*)(shift + col + 4);
            short8 o;
            o[0] = (short)f2bf(fmaxf(bf2f((u16)v[0]) * sa.x + ha.x, 0.f));
            o[1] = (short)f2bf(fmaxf(bf2f((u16)v[1]) * sa.y + ha.y, 0.f));
            o[2] = (short)f2bf(fmaxf(bf2f((u16)v[2]) * sa.z + ha.z, 0.f));
            o[3] = (short)f2bf(fmaxf(bf2f((u16)v[3]) * sa.w + ha.w, 0.f));
            o[4] = (short)f2bf(fmaxf(bf2f((u16)v[4]) * sb.x + hb.x, 0.f));
            o[5] = (short)f2bf(fmaxf(bf2f((u16)v[5]) * sb.y + hb.y, 0.f));
            o[6] = (short)f2bf(fmaxf(bf2f((u16)v[6]) * sb.z + hb.z, 0.f));
            o[7] = (short)f2bf(fmaxf(bf2f((u16)v[7]) * sb.w + hb.w, 0.f));
            av[s] = o;
        }
        __syncthreads();
        #pragma unroll
        for (int s = 0; s < 2; ++s) {
            int i = s * 256 + t;
            *(short8*)(As + i * 8) = av[s];
            int row = i >> 2, ch = i & 3;
            GLOAD16(Bt + (size_t)row * 256 + k0 + ch * 8, Bs + i * 8);
        }
        __syncthreads();
        short8 af[4], bfr[4];
        #pragma unroll
        for (int i = 0; i < 4; ++i) af[i] = *(const short8*)(As + aoff + i * 16 * 32);
        #pragma unroll
        for (int j = 0; j < 4; ++j) bfr[j] = *(const short8*)(Bs + boff + j * 16 * 32);
        #pragma unroll
        for (int i = 0; i < 4; ++i)
            #pragma unroll
            for (int j = 0; j < 4; ++j)
                acc[i][j] = __builtin_amdgcn_mfma_f32_16x16x32_bf16(af[i], bfr[j], acc[i][j], 0, 0, 0);
    }
    int rbase = m0 + (w >> 1) * 64 + (l >> 4) * 4;
    int cbase = (w & 1) * 64 + (l & 15);
    #pragma unroll
    for (int j = 0; j < 4; ++j)
        #pragma unroll
        for (int i = 0; i < 4; ++i)
            #pragma unroll
            for (int r = 0; r < 4; ++r) {
                int row = rbase + i * 16 + r;
                if (row < M) C[(size_t)row * 128 + cbase + j * 16] = f2bf(acc[i][j][r]);
            }
}

// gating GEMM with fused row-LN + relu + Wg2 dot + softmax -> gate[N][2]
__global__ __launch_bounds__(256) void k_mm_gate(const u16* A0, const u16* A1, const u16* A2,
                                                 const u16* B0, const u16* B1, const u16* B2,
                                                 const float* __restrict__ bg1,
                                                 const float* __restrict__ wlast,
                                                 const float* __restrict__ deg,
                                                 const float* __restrict__ ln_g,
                                                 const float* __restrict__ ln_b,
                                                 const float* __restrict__ Wg2,
                                                 const float* __restrict__ bg2,
                                                 float* __restrict__ gate, int M) {
    __shared__ __align__(16) u16 As[128 * 32];
    __shared__ __align__(16) u16 Bs[128 * 32];
    __shared__ float ps1[2][128], ps2[2][128], pt0[2][128], pt1[2][128];
    int m0 = blockIdx.x * 128;
    f32x4 acc[4][4]; mm_zero(acc);
    mm_core(A0, B0, 256, 256, 256, m0, 0, As, Bs, acc);
    mm_core(A1, B1, 256, 256, 256, m0, 0, As, Bs, acc);
    mm_core(A2, B2, 256, 256, 256, m0, 0, As, Bs, acc);
    int t = threadIdx.x, w = t >> 6, l = t & 63;
    int hcol = w & 1;
    int lr0 = (w >> 1) * 64 + (l >> 4) * 4;
    int cbase = hcol * 64 + (l & 15);
    float wl[4], bg[4], lg[4], lb[4], wa[4], wb_[4];
    #pragma unroll
    for (int j = 0; j < 4; ++j) {
        int col = cbase + j * 16;
        wl[j] = wlast[col]; bg[j] = bg1[col];
        lg[j] = ln_g[col];  lb[j] = ln_b[col];
        wa[j] = Wg2[col * 2 + 0]; wb_[j] = Wg2[col * 2 + 1];
    }
    #pragma unroll
    for (int i = 0; i < 4; ++i)
        #pragma unroll
        for (int r = 0; r < 4; ++r) {
            int row = m0 + lr0 + i * 16 + r;
            float dgv = (row < M) ? deg[row] : 0.f;
            float s1 = 0.f, s2 = 0.f;
            #pragma unroll
            for (int j = 0; j < 4; ++j) {
                float h = acc[i][j][r] + bg[j] + dgv * wl[j];
                acc[i][j][r] = h;
                s1 += h; s2 += h * h;
            }
            s1 = rsum16(s1); s2 = rsum16(s2);
            if ((l & 15) == 0) { ps1[hcol][lr0 + i * 16 + r] = s1; ps2[hcol][lr0 + i * 16 + r] = s2; }
        }
    __syncthreads();
    #pragma unroll
    for (int i = 0; i < 4; ++i)
        #pragma unroll
        for (int r = 0; r < 4; ++r) {
            int lr = lr0 + i * 16 + r;
            float s1 = ps1[0][lr] + ps1[1][lr];
            float s2 = ps2[0][lr] + ps2[1][lr];
            float mu = s1 * (1.f / 128.f);
            float var = s2 * (1.f / 128.f) - mu * mu;
            float is = 1.0f / sqrtf(var + 1e-5f);
            float t0 = 0.f, t1 = 0.f;
            #pragma unroll
            for (int j = 0; j < 4; ++j) {
                float y = fmaxf((acc[i][j][r] - mu) * is * lg[j] + lb[j], 0.f);
                t0 += y * wa[j]; t1 += y * wb_[j];
            }
            t0 = rsum16(t0); t1 = rsum16(t1);
            if ((l & 15) == 0) { pt0[hcol][lr] = t0; pt1[hcol][lr] = t1; }
        }
    __syncthreads();
    if (hcol == 0 && (l & 15) == 0) {
        float b20 = bg2[0], b21 = bg2[1];
        #pragma unroll
        for (int i = 0; i < 4; ++i)
            #pragma unroll
            for (int r = 0; r < 4; ++r) {
                int lr = lr0 + i * 16 + r;
                int row = m0 + lr;
                if (row >= M) continue;
                float t0 = (pt0[0][lr] + pt0[1][lr] + b20) * 0.5f;
                float t1 = (pt1[0][lr] + pt1[1][lr] + b21) * 0.5f;
                float m = fmaxf(t0, t1);
                float e0 = __expf(t0 - m), e1 = __expf(t1 - m);
                float inv = 1.0f / (e0 + e1);
                gate[(size_t)row * 2 + 0] = e0 * inv;
                gate[(size_t)row * 2 + 1] = e1 * inv;
            }
    }
}

// x@Wxp+bxp with fused bn2-apply (low = relu(S2*scale+shift), written here)
// and residual-LN -> resid (bf16). Kills the separate bn_relu pass.
__global__ __launch_bounds__(256) void k_mm_xp(const u16* __restrict__ A, const u16* __restrict__ Bt,
                                               const float* __restrict__ bias,
                                               const u16* __restrict__ S2,
                                               const float* __restrict__ scale,
                                               const float* __restrict__ shift,
                                               const float* __restrict__ g,
                                               const float* __restrict__ b,
                                               const float* __restrict__ rs_ptr,
                                               float* __restrict__ low_out,
                                               u16* __restrict__ resid, int M) {
    __shared__ __align__(16) u16 As[128 * 32];
    __shared__ __align__(16) u16 Bs[128 * 32];
    __shared__ float ps1[2][128], ps2[2][128];
    int m0 = blockIdx.x * 128;
    f32x4 acc[4][4]; mm_zero(acc);
    mm_core(A, Bt, 256, 256, 256, m0, 0, As, Bs, acc);
    int t = threadIdx.x, w = t >> 6, l = t & 63;
    int hcol = w & 1;
    int lr0 = (w >> 1) * 64 + (l >> 4) * 4;
    int cbase = hcol * 64 + (l & 15);
    float rs = rs_ptr[0];
    float bx[4], lg[4], lb[4], sc_[4], sh_[4];
    #pragma unroll
    for (int j = 0; j < 4; ++j) {
        int col = cbase + j * 16;
        bx[j] = bias[col]; lg[j] = g[col]; lb[j] = b[col];
        sc_[j] = scale[col]; sh_[j] = shift[col];
    }
    #pragma unroll
    for (int i = 0; i < 4; ++i)
        #pragma unroll
        for (int r = 0; r < 4; ++r) {
            int row = m0 + lr0 + i * 16 + r;
            float s1 = 0.f, s2 = 0.f;
            #pragma unroll
            for (int j = 0; j < 4; ++j) {
                float lv = 0.f;
                if (row < M) {
                    float s2v = bf2f(S2[(size_t)row * 128 + cbase + j * 16]);
                    lv = fmaxf(s2v * sc_[j] + sh_[j], 0.f);
                    low_out[(size_t)row * 128 + cbase + j * 16] = lv;
                }
                float h = rs * (acc[i][j][r] + bx[j] - lv);
                acc[i][j][r] = h;
                s1 += h; s2 += h * h;
            }
            s1 = rsum16(s1); s2 = rsum16(s2);
            if ((l & 15) == 0) { ps1[hcol][lr0 + i * 16 + r] = s1; ps2[hcol][lr0 + i * 16 + r] = s2; }
        }
    __syncthreads();
    #pragma unroll
    for (int i = 0; i < 4; ++i)
        #pragma unroll
        for (int r = 0; r < 4; ++r) {
            int lr = lr0 + i * 16 + r;
            int row = m0 + lr;
            float s1 = ps1[0][lr] + ps1[1][lr];
            float s2 = ps2[0][lr] + ps2[1][lr];
            float mu = s1 * (1.f / 128.f);
            float var = s2 * (1.f / 128.f) - mu * mu;
            float is = 1.0f / sqrtf(var + 1e-5f);
            if (row < M) {
                #pragma unroll
                for (int j = 0; j < 4; ++j) {
                    float y = (acc[i][j][r] - mu) * is * lg[j] + lb[j];
                    resid[(size_t)row * 128 + cbase + j * 16] = f2bf(y);
                }
            }
        }
}

// Q -> bf16 Qb; K/V -> bf16 interleaved KV[N][256]  (R4-proven 3-dispatch form)
__global__ __launch_bounds__(256) void k_mm_qkv(const u16* __restrict__ A,
                                                const u16* Wqt, const u16* Wkt, const u16* Wvt,
                                                u16* Qb, u16* KV, int M) {
    __shared__ __align__(16) u16 As[128 * 32];
    __shared__ __align__(16) u16 Bs[128 * 32];
    int z = blockIdx.z;
    const u16* Bt = (z == 0) ? Wqt : (z == 1) ? Wkt : Wvt;
    int m0 = blockIdx.x * 128;
    f32x4 acc[4][4]; mm_zero(acc);
    mm_core(A, Bt, 128, 128, 128, m0, 0, As, Bs, acc);
    int t = threadIdx.x, w = t >> 6, l = t & 63;
    int rbase = m0 + (w >> 1) * 64 + (l >> 4) * 4;
    int cbase = (w & 1) * 64 + (l & 15);
    if (z == 0) {
        #pragma unroll
        for (int j = 0; j < 4; ++j)
            #pragma unroll
            for (int i = 0; i < 4; ++i)
                #pragma unroll
                for (int r = 0; r < 4; ++r) {
                    int row = rbase + i * 16 + r;
                    if (row < M) Qb[(size_t)row * 128 + cbase + j * 16] = f2bf(acc[i][j][r]);
                }
    } else {
        int coff = (z == 1) ? 0 : 128;
        #pragma unroll
        for (int j = 0; j < 4; ++j)
            #pragma unroll
            for (int i = 0; i < 4; ++i)
                #pragma unroll
                for (int r = 0; r < 4; ++r) {
                    int row = rbase + i * 16 + r;
                    if (row < M) KV[(size_t)row * 256 + coff + cbase + j * 16] = f2bf(acc[i][j][r]);
                }
    }
}

// ---------------------------------------------------------------------------
// BatchNorm (bf16 input) — bn2 stats only (apply fused into k_mm_xp)
// ---------------------------------------------------------------------------
__global__ void k_bn_stats_bf(const u16* __restrict__ H, double* __restrict__ stats, int N, int C) {
    int t = threadIdx.x;
    int rpt = 256 / C;
    int rsub = t / C;
    int col = t - rsub * C;
    double s = 0.0, q = 0.0;
    for (long r = (long)blockIdx.x * rpt + rsub; r < N; r += (long)gridDim.x * rpt) {
        float v = bf2f(H[(size_t)r * C + col]);
        s += v; q += (double)v * v;
    }
    __shared__ double sh_s[256], sh_q[256];
    sh_s[t] = s; sh_q[t] = q;
    __syncthreads();
    if (t < C) {
        for (int k = 1; k < rpt; ++k) { s += sh_s[t + k * C]; q += sh_q[t + k * C]; }
        atomicAdd(&stats[t], s);
        atomicAdd(&stats[C + t], q);
    }
}

__global__ void k_bn_fin(const double* __restrict__ stats, const float* __restrict__ g,
                         const float* __restrict__ b, float* __restrict__ scale,
                         float* __restrict__ shift, int C, double invN) {
    int t = threadIdx.x;
    if (t >= C) return;
    double mean = stats[t] * invN;
    double var = stats[C + t] * invN - mean * mean;
    float sc = (float)((double)g[t] / sqrt(var + 1e-5));
    scale[t] = sc;
    shift[t] = b[t] - (float)mean * sc;
}

// ---------------------------------------------------------------------------
// fused attention: 8 edges/iter, 16-lane groups for score, KV interleaved.
// nt hints ONLY on last-use streams (cv/low loads, high/outp stores) so the
// 51MB KV table stays resident in L3; KV/Qb loads keep normal policy.
// ---------------------------------------------------------------------------
__global__ void k_attn_aggr(const u16* __restrict__ Qb, const u16* __restrict__ KV,
                            const int* __restrict__ row_ptr, const int2* __restrict__ cv,
                            const float* __restrict__ gate, const float* __restrict__ low,
                            float* __restrict__ high, float* __restrict__ outp, int N) {
    int wid = blockIdx.x * 4 + (threadIdx.x >> 6);
    if (wid >= N) return;
    int lane = threadIdx.x & 63;
    int sub = lane & 15;
    int g = lane >> 4;
    float qs[8];
    {
        short8 q8 = *(const short8*)(Qb + (size_t)wid * HD + sub * 8);
        #pragma unroll
        for (int k = 0; k < 8; ++k) qs[k] = bf2f((u16)q8[k]);
    }
    float2 qv;
    {
        ushort2 qt = *(const ushort2*)(Qb + (size_t)wid * HD + lane * 2);
        qv.x = bf2f(qt.x); qv.y = bf2f(qt.y);
    }
    float n0 = 0, n1 = 0, den = 0;
    int s = row_ptr[wid], e = row_ptr[wid + 1];
    int j = s;
    for (; j + 7 < e; j += 8) {
        long long cl0 = __builtin_nontemporal_load((const long long*)(cv + j + g));
        long long cl1 = __builtin_nontemporal_load((const long long*)(cv + j + 4 + g));
        int cg0 = (int)cl0;
        int cg1 = (int)cl1;
        short8 ka = *(const short8*)(KV + (size_t)cg0 * 256 + sub * 8);
        short8 kb = *(const short8*)(KV + (size_t)cg1 * 256 + sub * 8);
        float p0 = qs[0] * bf2f((u16)ka[0]) + qs[1] * bf2f((u16)ka[1])
                 + qs[2] * bf2f((u16)ka[2]) + qs[3] * bf2f((u16)ka[3])
                 + qs[4] * bf2f((u16)ka[4]) + qs[5] * bf2f((u16)ka[5])
                 + qs[6] * bf2f((u16)ka[6]) + qs[7] * bf2f((u16)ka[7]);
        float p1 = qs[0] * bf2f((u16)kb[0]) + qs[1] * bf2f((u16)kb[1])
                 + qs[2] * bf2f((u16)kb[2]) + qs[3] * bf2f((u16)kb[3])
                 + qs[4] * bf2f((u16)kb[4]) + qs[5] * bf2f((u16)kb[5])
                 + qs[6] * bf2f((u16)kb[6]) + qs[7] * bf2f((u16)kb[7]);
        p0 += __shfl_xor(p0, 1); p1 += __shfl_xor(p1, 1);
        p0 += __shfl_xor(p0, 2); p1 += __shfl_xor(p1, 2);
        p0 += __shfl_xor(p0, 4); p1 += __shfl_xor(p1, 4);
        p0 += __shfl_xor(p0, 8); p1 += __shfl_xor(p1, 8);
        float sc0 = p0 * 0.08838834764831845f;
        float sc1 = p1 * 0.08838834764831845f;
        float ls0 = sc0 > 0.f ? sc0 : 0.2f * sc0;
        float ls1 = sc1 > 0.f ? sc1 : 0.2f * sc1;
        float ex0 = __expf(ls0);
        float ex1 = __expf(ls1);
        float exb[8]; int cb[8];
        #pragma unroll
        for (int t = 0; t < 4; ++t) {
            exb[t]     = __shfl(ex0, t << 4); cb[t]     = __shfl(cg0, t << 4);
            exb[4 + t] = __shfl(ex1, t << 4); cb[4 + t] = __shfl(cg1, t << 4);
        }
        ushort2 vb[8];
        #pragma unroll
        for (int t = 0; t < 8; ++t) vb[t] = *(const ushort2*)(KV + (size_t)cb[t] * 256 + 128 + lane * 2);
        #pragma unroll
        for (int t = 0; t < 8; ++t) {
            n0 += exb[t] * bf2f(vb[t].x);
            n1 += exb[t] * bf2f(vb[t].y);
            den += exb[t];
        }
    }
    for (; j + 3 < e; j += 4) {
        long long cl = __builtin_nontemporal_load((const long long*)(cv + j + g));
        int cg = (int)cl;
        short8 kk = *(const short8*)(KV + (size_t)cg * 256 + sub * 8);
        float p = qs[0] * bf2f((u16)kk[0]) + qs[1] * bf2f((u16)kk[1])
                + qs[2] * bf2f((u16)kk[2]) + qs[3] * bf2f((u16)kk[3])
                + qs[4] * bf2f((u16)kk[4]) + qs[5] * bf2f((u16)kk[5])
                + qs[6] * bf2f((u16)kk[6]) + qs[7] * bf2f((u16)kk[7]);
        p += __shfl_xor(p, 1); p += __shfl_xor(p, 2);
        p += __shfl_xor(p, 4); p += __shfl_xor(p, 8);
        float sc = p * 0.08838834764831845f;
        float ls = sc > 0.f ? sc : 0.2f * sc;
        float ex = __expf(ls);
        float exb[4]; int cb[4];
        #pragma unroll
        for (int t = 0; t < 4; ++t) { exb[t] = __shfl(ex, t << 4); cb[t] = __shfl(cg, t << 4); }
        ushort2 vb[4];
        #pragma unroll
        for (int t = 0; t < 4; ++t) vb[t] = *(const ushort2*)(KV + (size_t)cb[t] * 256 + 128 + lane * 2);
        #pragma unroll
        for (int t = 0; t < 4; ++t) {
            n0 += exb[t] * bf2f(vb[t].x);
            n1 += exb[t] * bf2f(vb[t].y);
            den += exb[t];
        }
    }
    for (; j < e; ++j) {
        long long cl = __builtin_nontemporal_load((const long long*)(cv + j));
        int c0 = (int)cl;
        ushort2 kb0 = *(const ushort2*)(KV + (size_t)c0 * 256 + lane * 2);
        ushort2 vb0 = *(const ushort2*)(KV + (size_t)c0 * 256 + 128 + lane * 2);
        float sc0 = qv.x * bf2f(kb0.x) + qv.y * bf2f(kb0.y);
        #pragma unroll
        for (int off = 32; off > 0; off >>= 1) sc0 += __shfl_xor(sc0, off);
        float p = sc0 * 0.08838834764831845f;
        float ls = p > 0.f ? p : 0.2f * p;
        float ex = __expf(ls);
        n0 += ex * bf2f(vb0.x); n1 += ex * bf2f(vb0.y); den += ex;
    }
    float inv = 1.0f / (den + 1e-16f);
    float h0 = n0 * inv, h1 = n1 * inv;
    f32x2 hh = {h0, h1};
    __builtin_nontemporal_store(hh, (f32x2*)(high + (size_t)wid * HD + lane * 2));
    float g0 = gate[(size_t)wid * 2 + 0], g1 = gate[(size_t)wid * 2 + 1];
    f32x2 lw = __builtin_nontemporal_load((const f32x2*)(low + (size_t)wid * HD + lane * 2));
    f32x2 oo = {g0 * lw[0] + g1 * h0, g0 * lw[1] + g1 * h1};
    __builtin_nontemporal_store(oo, (f32x2*)(outp + (size_t)wid * HD + lane * 2));
}

// ---------------------------------------------------------------------------
extern "C" void kernel_launch(void* const* d_in, const int* in_sizes, int n_in,
                              void* d_out, int out_size, void* d_ws, size_t ws_size,
                              hipStream_t stream) {
    const float* x      = (const float*)d_in[0];
    const int*   erow   = (const int*)d_in[1];
    const int*   ecol   = (const int*)d_in[2];
    const float* avals  = (const float*)d_in[3];
    const float* W_gc1  = (const float*)d_in[4];
    const float* bn1_g  = (const float*)d_in[6];
    const float* bn1_b  = (const float*)d_in[7];
    const float* W_gc2  = (const float*)d_in[8];
    const float* bn2_g  = (const float*)d_in[10];
    const float* bn2_b  = (const float*)d_in[11];
    const float* Wg1    = (const float*)d_in[12];
    const float* bg1    = (const float*)d_in[13];
    const float* ln_g   = (const float*)d_in[14];
    const float* ln_b   = (const float*)d_in[15];
    const float* Wg2    = (const float*)d_in[16];
    const float* bg2    = (const float*)d_in[17];
    const float* Wxp    = (const float*)d_in[18];
    const float* bxp    = (const float*)d_in[19];
    const float* rscale = (const float*)d_in[20];
    const float* rn_g   = (const float*)d_in[21];
    const float* rn_b   = (const float*)d_in[22];
    const float* Wq     = (const float*)d_in[23];
    const float* Wk     = (const float*)d_in[24];
    const float* Wv     = (const float*)d_in[25];

    const int N = in_sizes[0] / F0;   // 100000
    const int E = in_sizes[1];        // 3200000

    char* base = (char*)d_ws;
    size_t off = 0;
    auto carve = [&](size_t bytes) -> char* {
        char* p = base + off;
        off += (bytes + 255) & ~(size_t)255;
        return p;
    };
    double* stats  = (double*)carve(4096);
    float* scaleb  = (float*)carve(1024);
    float* shiftb  = (float*)carve(1024);
    int*   partials= (int*)carve(2048);
    u16* Wgc1t = (u16*)carve(65536 * 2);
    u16* Wgc2t = (u16*)carve(32768 * 2);
    u16* Wdt   = (u16*)carve(32768 * 2);
    u16* W1t   = (u16*)carve(32768 * 2);
    u16* W2t   = (u16*)carve(32768 * 2);
    u16* Wxpt  = (u16*)carve(32768 * 2);
    u16* Wqt   = (u16*)carve(16384 * 2);
    u16* Wkt   = (u16*)carve(16384 * 2);
    u16* Wvt   = (u16*)carve(16384 * 2);
    int*   row_ptr = (int*)carve((size_t)(N + 1) * 4);
    int*   cursor  = (int*)carve((size_t)N * 4);   // hist counts
    float* deg     = (float*)carve((size_t)N * 4);
    int2*  cv      = (int2*)carve((size_t)E * 8);        // packed (col, val)
    u16*   x_bf    = (u16*)carve((size_t)NP * F0 * 2);
    u16*   kvb     = (u16*)carve((size_t)NP * 256 * 2);  // KV interleaved [N][256]
    u16*   AX_bf   = (u16*)carve((size_t)NP * F0 * 2);
    u16*   XSTD_bf = (u16*)carve((size_t)NP * F0 * 2);
    u16*   h1_bf   = (u16*)carve((size_t)NP * F0 * 2);   // S1 bf16 -> resid
    u16*   S2_bf   = (u16*)carve((size_t)NP * HD * 2);
    u16*   G2_bf   = (u16*)carve((size_t)NP * HD * 2);
    float* M3      = (float*)carve((size_t)NP * HD * 4); // rank -> Qb
    (void)ws_size; (void)n_in; (void)out_size;

    u16*   S1_bf = h1_bf;
    u16*   resid_bf = h1_bf;                       // S1 dead after gc2 GEMM
    int*   rank  = (int*)M3;                       // dead after scatter
    u16*   Qb    = (u16*)M3;                       // live from mm_qkv on

    float* out_o    = (float*)d_out;
    float* out_gate = out_o + (size_t)N * HD;
    float* out_low  = out_gate + (size_t)N * 2;
    float* out_high = out_low + (size_t)N * HD;

    const int eb  = (E + 255) / 256;
    const int wb  = (N + 3) / 4;
    const int NB1 = (N + 1023) / 1024;
    const int gx  = (N + 127) / 128;
    const dim3 blk(256);

    // ===== CSR (hist+rank -> scan -> atomic-free scatter) =====
    hipMemsetAsync(cursor, 0, (size_t)N * 4, stream);
    k_hist_rank<<<eb, blk, 0, stream>>>(erow, cursor, rank, E);
    k_scan_blk<<<NB1, 1024, 0, stream>>>(cursor, row_ptr + 1, partials, N);
    k_scan_part<<<1, 128, 0, stream>>>(partials, NB1);
    k_scan_add<<<NB1, 1024, 0, stream>>>(row_ptr, partials, N);
    k_scatter_direct<<<eb, blk, 0, stream>>>(erow, ecol, avals, rank, row_ptr, cv, E);

    // ===== casts =====
    k_cast_x<<<(N * 64 + 255) / 256, blk, 0, stream>>>(x, x_bf, N * 64);
    k_prep_w<<<dim3(256, 1, 9), blk, 0, stream>>>(W_gc1, W_gc2, Wg1, Wxp, Wq, Wk, Wv,
                                                  Wgc1t, Wgc2t, Wdt, W1t, W2t, Wxpt, Wqt, Wkt, Wvt);

    // ===== spmm over x (fused finalize: AX_bf, XSTD_bf, deg directly) =====
    k_spmm_x2<<<wb, blk, 0, stream>>>(x_bf, row_ptr, cv, AX_bf, XSTD_bf, deg, N);

    // ===== low path (bn1 stats fused in gc1; bn1 apply fused in gc2 staging) =====
    hipMemsetAsync(stats, 0, 4096, stream);
    k_mm_gc1<<<dim3(gx, 2), blk, 0, stream>>>(AX_bf, Wgc1t, S1_bf, stats, N);
    k_bn_fin<<<1, blk, 0, stream>>>(stats, bn1_g, bn1_b, scaleb, shiftb, 256, 1.0 / N);
    k_mm_gc2<<<dim3(gx, 1), blk, 0, stream>>>(S1_bf, Wgc2t, scaleb, shiftb, G2_bf, N);
    k_spmm128<<<wb, blk, 0, stream>>>(G2_bf, row_ptr, cv, S2_bf, N);
    hipMemsetAsync(stats, 0, 2048, stream);
    k_bn_stats_bf<<<1024, blk, 0, stream>>>(S2_bf, stats, N, 128);
    k_bn_fin<<<1, blk, 0, stream>>>(stats, bn2_g, bn2_b, scaleb, shiftb, 128, 1.0 / N);

    // ===== gating (fused GEMM + LN + softmax) =====
    k_mm_gate<<<dim3(gx, 1), blk, 0, stream>>>(x_bf, AX_bf, XSTD_bf, Wdt, W1t, W2t,
                                               bg1, Wg1 + (size_t)768 * 128, deg,
                                               ln_g, ln_b, Wg2, bg2, out_gate, N);

    // ===== high path (bn2 apply + low write fused into xp) =====
    k_mm_xp<<<dim3(gx, 1), blk, 0, stream>>>(x_bf, Wxpt, bxp, S2_bf, scaleb, shiftb,
                                             rn_g, rn_b, rscale, out_low, resid_bf, N);
    k_mm_qkv<<<dim3(gx, 1, 3), blk, 0, stream>>>(resid_bf, Wqt, Wkt, Wvt, Qb, kvb, N);
    k_attn_aggr<<<wb, blk, 0, stream>>>(Qb, kvb, row_ptr, cv, out_gate, out_low, out_high, out_o, N);
}

// Round 10
// 1345.790 us; speedup vs baseline: 1.1367x; 1.0095x over previous
//
#include <hip/hip_runtime.h>

#define F0 256
#define HD 128
#define NP 100352   // padded rows (784*128)

typedef unsigned short u16;
typedef __attribute__((ext_vector_type(8))) short short8;
typedef __attribute__((ext_vector_type(4))) float f32x4;

__device__ inline float bf2f(u16 u) {
    union { unsigned int i; float f; } v; v.i = ((unsigned int)u) << 16; return v.f;
}
__device__ inline u16 f2bf(float f) {
    union { float f; unsigned int i; } v; v.f = f;
    unsigned int r = v.i + 0x7FFF + ((v.i >> 16) & 1);
    return (u16)(r >> 16);
}

// 4-level butterfly over the 16-lane group (l&15)
__device__ inline float rsum16(float v) {
    v += __shfl_xor(v, 1); v += __shfl_xor(v, 2);
    v += __shfl_xor(v, 4); v += __shfl_xor(v, 8);
    return v;
}

#define GLOAD16(gp, lp) __builtin_amdgcn_global_load_lds( \
    (const __attribute__((address_space(1))) void*)(gp), \
    (__attribute__((address_space(3))) void*)(lp), 16, 0, 0)

// ---------------------------------------------------------------------------
// CSR build: hist(+rank) -> scan -> atomic-free scatter
// ---------------------------------------------------------------------------
__global__ void k_hist_rank(const int* __restrict__ row, int* __restrict__ counts,
                            int* __restrict__ rank, int E) {
    int e = blockIdx.x * blockDim.x + threadIdx.x;
    if (e < E) rank[e] = atomicAdd(&counts[row[e]], 1);
}

__global__ void k_scan_blk(const int* __restrict__ counts, int* __restrict__ scan_out,
                           int* __restrict__ partials, int n) {
    __shared__ int wsum[16];
    int t = threadIdx.x;
    int i = blockIdx.x * 1024 + t;
    int v = (i < n) ? counts[i] : 0;
    int lane = t & 63, w = t >> 6;
    #pragma unroll
    for (int off = 1; off < 64; off <<= 1) { int u = __shfl_up(v, off); if (lane >= off) v += u; }
    if (lane == 63) wsum[w] = v;
    __syncthreads();
    if (t < 16) {
        int s = wsum[t];
        #pragma unroll
        for (int off = 1; off < 16; off <<= 1) { int u = __shfl_up(s, off); if (t >= off) s += u; }
        wsum[t] = s;
    }
    __syncthreads();
    int add = (w > 0) ? wsum[w - 1] : 0;
    if (i < n) scan_out[i] = v + add;
    if (t == 1023) partials[blockIdx.x] = wsum[15];
}

__global__ void k_scan_part(int* partials, int nb) {
    __shared__ int ws2[2];
    int t = threadIdx.x;
    int v = (t < nb) ? partials[t] : 0;
    int lane = t & 63, w = t >> 6;
    #pragma unroll
    for (int off = 1; off < 64; off <<= 1) { int u = __shfl_up(v, off); if (lane >= off) v += u; }
    if (lane == 63) ws2[w] = v;
    __syncthreads();
    if (w == 1) v += ws2[0];
    if (t < nb) partials[t] = v;
}

__global__ void k_scan_add(int* __restrict__ row_ptr, const int* __restrict__ partials, int n) {
    int b = blockIdx.x;
    int i = b * 1024 + threadIdx.x;
    if (b == 0 && threadIdx.x == 0) row_ptr[0] = 0;
    int add = (b > 0) ? partials[b - 1] : 0;
    if (i < n) row_ptr[1 + i] += add;
}

__global__ void k_scatter_direct(const int* __restrict__ row, const int* __restrict__ ecol,
                                 const float* __restrict__ avals, const int* __restrict__ rank,
                                 const int* __restrict__ row_ptr, int2* __restrict__ cv, int E) {
    int e = blockIdx.x * blockDim.x + threadIdx.x;
    if (e >= E) return;
    int r = row[e];
    int c = __builtin_nontemporal_load(ecol + e);
    float v = __builtin_nontemporal_load(avals + e);
    int rk = __builtin_nontemporal_load(rank + e);
    int pos = row_ptr[r] + rk;
    cv[pos] = make_int2(c, __float_as_int(v));
}

// ---------------------------------------------------------------------------
// casts
// ---------------------------------------------------------------------------
__global__ void k_cast_x(const float* __restrict__ x, u16* __restrict__ xb, int total4) {
    int i = blockIdx.x * blockDim.x + threadIdx.x;
    if (i >= total4) return;
    float4 v = ((const float4*)x)[i];
    ((ushort4*)xb)[i] = make_ushort4(f2bf(v.x), f2bf(v.y), f2bf(v.z), f2bf(v.w));
}

__global__ void k_prep_w(const float* __restrict__ W_gc1, const float* __restrict__ W_gc2,
                         const float* __restrict__ Wg1, const float* __restrict__ Wxp,
                         const float* __restrict__ Wq, const float* __restrict__ Wk,
                         const float* __restrict__ Wv,
                         u16* Wgc1t, u16* Wgc2t, u16* Wdt, u16* W1t, u16* W2t,
                         u16* Wxpt, u16* Wqt, u16* Wkt, u16* Wvt) {
    int z = blockIdx.z;
    int idx = blockIdx.x * 256 + threadIdx.x;
    if (z == 0) { if (idx < 65536) { int n = idx >> 8, k = idx & 255; Wgc1t[idx] = f2bf(W_gc1[k * 256 + n]); } }
    else if (z == 1) { if (idx < 32768) { int n = idx >> 8, k = idx & 255; Wgc2t[idx] = f2bf(W_gc2[k * 128 + n]); } }
    else if (z == 2) { if (idx < 32768) { int n = idx >> 8, k = idx & 255; Wdt[idx] = f2bf(Wg1[k * 128 + n] - Wg1[(k + 256) * 128 + n]); } }
    else if (z == 3) { if (idx < 32768) { int n = idx >> 8, k = idx & 255; W1t[idx] = f2bf(Wg1[(k + 256) * 128 + n]); } }
    else if (z == 4) { if (idx < 32768) { int n = idx >> 8, k = idx & 255; W2t[idx] = f2bf(Wg1[(k + 512) * 128 + n]); } }
    else if (z == 5) { if (idx < 32768) { int n = idx >> 8, k = idx & 255; Wxpt[idx] = f2bf(Wxp[k * 128 + n]); } }
    else if (z == 6) { if (idx < 16384) { int n = idx >> 7, k = idx & 127; Wqt[idx] = f2bf(Wq[k * 128 + n]); } }
    else if (z == 7) { if (idx < 16384) { int n = idx >> 7, k = idx & 127; Wkt[idx] = f2bf(Wk[k * 128 + n]); } }
    else if (z == 8) { if (idx < 16384) { int n = idx >> 7, k = idx & 127; Wvt[idx] = f2bf(Wv[k * 128 + n]); } }
}

// ---------------------------------------------------------------------------
// SpMM over x with fused mean/std finalize (unroll-8)
// ---------------------------------------------------------------------------
__global__ void k_spmm_x2(const u16* __restrict__ Xb, const int* __restrict__ row_ptr,
                          const int2* __restrict__ cv,
                          u16* __restrict__ AXb, u16* __restrict__ XSTDb,
                          float* __restrict__ deg, int N) {
    int wid = blockIdx.x * 4 + (threadIdx.x >> 6);
    if (wid >= N) return;
    int lane = threadIdx.x & 63;
    float a0 = 0, a1 = 0, a2 = 0, a3 = 0;
    float q0 = 0, q1 = 0, q2 = 0, q3 = 0, d = 0;
    int s = row_ptr[wid], e = row_ptr[wid + 1];
    int j = s;
    for (; j + 7 < e; j += 8) {
        int2 cc[8]; ushort4 xb[8];
        #pragma unroll
        for (int t = 0; t < 8; ++t) cc[t] = cv[j + t];
        #pragma unroll
        for (int t = 0; t < 8; ++t) xb[t] = *(const ushort4*)(Xb + (size_t)cc[t].x * F0 + lane * 4);
        #pragma unroll
        for (int t = 0; t < 8; ++t) {
            float x0 = bf2f(xb[t].x), x1 = bf2f(xb[t].y), x2 = bf2f(xb[t].z), x3 = bf2f(xb[t].w);
            float vv = __int_as_float(cc[t].y);
            a0 += vv * x0; a1 += vv * x1; a2 += vv * x2; a3 += vv * x3;
            q0 += vv * x0 * x0; q1 += vv * x1 * x1; q2 += vv * x2 * x2; q3 += vv * x3 * x3;
            d += vv;
        }
    }
    for (; j < e; ++j) {
        int2 cc = cv[j];
        float v0 = __int_as_float(cc.y);
        ushort4 xb0 = *(const ushort4*)(Xb + (size_t)cc.x * F0 + lane * 4);
        float x0 = bf2f(xb0.x), x1 = bf2f(xb0.y), x2 = bf2f(xb0.z), x3 = bf2f(xb0.w);
        a0 += v0 * x0; a1 += v0 * x1; a2 += v0 * x2; a3 += v0 * x3;
        q0 += v0 * x0 * x0; q1 += v0 * x1 * x1; q2 += v0 * x2 * x2; q3 += v0 * x3 * x3;
        d += v0;
    }
    float inv = 1.0f / (d + 1e-8f);
    float m0 = a0 * inv, m1 = a1 * inv, m2 = a2 * inv, m3 = a3 * inv;
    float s0 = sqrtf(fmaxf(q0 * inv - m0 * m0, 0.f));
    float s1 = sqrtf(fmaxf(q1 * inv - m1 * m1, 0.f));
    float s2 = sqrtf(fmaxf(q2 * inv - m2 * m2, 0.f));
    float s3 = sqrtf(fmaxf(q3 * inv - m3 * m3, 0.f));
    *(ushort4*)(AXb + (size_t)wid * F0 + lane * 4) = make_ushort4(f2bf(a0), f2bf(a1), f2bf(a2), f2bf(a3));
    *(ushort4*)(XSTDb + (size_t)wid * F0 + lane * 4) = make_ushort4(f2bf(s0), f2bf(s1), f2bf(s2), f2bf(s3));
    if (lane == 0) deg[wid] = d;
}

// bf16 in, bf16 out (unroll-8)
__global__ void k_spmm128(const u16* __restrict__ Xb, const int* __restrict__ row_ptr,
                          const int2* __restrict__ cv, u16* __restrict__ OUT, int N) {
    int wid = blockIdx.x * 4 + (threadIdx.x >> 6);
    if (wid >= N) return;
    int lane = threadIdx.x & 63;
    float a0 = 0, a1 = 0;
    int s = row_ptr[wid], e = row_ptr[wid + 1];
    int j = s;
    for (; j + 7 < e; j += 8) {
        int2 cc[8]; ushort2 xb[8];
        #pragma unroll
        for (int t = 0; t < 8; ++t) cc[t] = cv[j + t];
        #pragma unroll
        for (int t = 0; t < 8; ++t) xb[t] = *(const ushort2*)(Xb + (size_t)cc[t].x * HD + lane * 2);
        #pragma unroll
        for (int t = 0; t < 8; ++t) {
            float vv = __int_as_float(cc[t].y);
            a0 += vv * bf2f(xb[t].x); a1 += vv * bf2f(xb[t].y);
        }
    }
    for (; j < e; ++j) {
        int2 cc = cv[j];
        float v0 = __int_as_float(cc.y);
        ushort2 x0 = *(const ushort2*)(Xb + (size_t)cc.x * HD + lane * 2);
        a0 += v0 * bf2f(x0.x); a1 += v0 * bf2f(x0.y);
    }
    *(ushort2*)(OUT + (size_t)wid * HD + lane * 2) = make_ushort2(f2bf(a0), f2bf(a1));
}

// ---------------------------------------------------------------------------
// bf16 MFMA GEMM core: C[128,128] tile = A[M,K] @ Bt[N,K]^T, BK=32
// ---------------------------------------------------------------------------
__device__ inline void mm_core(const u16* __restrict__ A, const u16* __restrict__ Bt,
                               int K, int ldA, int ldB, int m0, int n0,
                               u16* As, u16* Bs, f32x4 acc[4][4]) {
    int t = threadIdx.x, w = t >> 6, l = t & 63;
    int wr = (w >> 1) * 64, wc = (w & 1) * 64;
    int aoff = (wr + (l & 15)) * 32 + (l >> 4) * 8;
    int boff = (wc + (l & 15)) * 32 + (l >> 4) * 8;
    for (int k0 = 0; k0 < K; k0 += 32) {
        __syncthreads();
        #pragma unroll
        for (int s = 0; s < 2; ++s) {
            int i = s * 256 + t;
            int row = i >> 2, ch = i & 3;
            GLOAD16(A + (size_t)(m0 + row) * ldA + k0 + ch * 8, As + i * 8);
            GLOAD16(Bt + (size_t)(n0 + row) * ldB + k0 + ch * 8, Bs + i * 8);
        }
        __syncthreads();
        short8 af[4], bfr[4];
        #pragma unroll
        for (int i = 0; i < 4; ++i) af[i] = *(const short8*)(As + aoff + i * 16 * 32);
        #pragma unroll
        for (int j = 0; j < 4; ++j) bfr[j] = *(const short8*)(Bs + boff + j * 16 * 32);
        #pragma unroll
        for (int i = 0; i < 4; ++i)
            #pragma unroll
            for (int j = 0; j < 4; ++j)
                acc[i][j] = __builtin_amdgcn_mfma_f32_16x16x32_bf16(af[i], bfr[j], acc[i][j], 0, 0, 0);
    }
}

__device__ inline void mm_zero(f32x4 acc[4][4]) {
    #pragma unroll
    for (int i = 0; i < 4; ++i)
        #pragma unroll
        for (int j = 0; j < 4; ++j)
            acc[i][j] = (f32x4){0.f, 0.f, 0.f, 0.f};
}

// gc1 GEMM (AX @ Wgc1 -> S1 bf16) with fused per-column BN stats accumulation
__global__ __launch_bounds__(256) void k_mm_gc1(const u16* __restrict__ A, const u16* __restrict__ Bt,
                                                u16* __restrict__ C, double* __restrict__ stats, int M) {
    __shared__ __align__(16) u16 As[128 * 32];
    __shared__ __align__(16) u16 Bs[128 * 32];
    __shared__ float cs1[2][128], cs2[2][128];
    int m0 = blockIdx.x * 128, n0 = blockIdx.y * 128;
    f32x4 acc[4][4]; mm_zero(acc);
    mm_core(A, Bt, 256, 256, 256, m0, n0, As, Bs, acc);
    int t = threadIdx.x, w = t >> 6, l = t & 63;
    int rbase = m0 + (w >> 1) * 64 + (l >> 4) * 4;
    int cbase = n0 + (w & 1) * 64 + (l & 15);
    float sj1[4], sj2[4];
    #pragma unroll
    for (int j = 0; j < 4; ++j) { sj1[j] = 0.f; sj2[j] = 0.f; }
    #pragma unroll
    for (int j = 0; j < 4; ++j)
        #pragma unroll
        for (int i = 0; i < 4; ++i)
            #pragma unroll
            for (int r = 0; r < 4; ++r) {
                int row = rbase + i * 16 + r;
                if (row < M) {
                    float h = acc[i][j][r];
                    C[(size_t)row * 256 + cbase + j * 16] = f2bf(h);
                    sj1[j] += h; sj2[j] += h * h;
                }
            }
    // lanes l, l^16, l^32, l^48 hold the same columns (different rows)
    #pragma unroll
    for (int j = 0; j < 4; ++j) {
        sj1[j] += __shfl_xor(sj1[j], 16); sj1[j] += __shfl_xor(sj1[j], 32);
        sj2[j] += __shfl_xor(sj2[j], 16); sj2[j] += __shfl_xor(sj2[j], 32);
    }
    if (l < 16) {
        #pragma unroll
        for (int j = 0; j < 4; ++j) {
            int col = (w & 1) * 64 + l + j * 16;
            cs1[w >> 1][col] = sj1[j];
            cs2[w >> 1][col] = sj2[j];
        }
    }
    __syncthreads();
    if (t < 128) {
        double s = (double)cs1[0][t] + (double)cs1[1][t];
        atomicAdd(&stats[n0 + t], s);
    } else {
        int c = t - 128;
        double q = (double)cs2[0][c] + (double)cs2[1][c];
        atomicAdd(&stats[256 + n0 + c], q);
    }
}

// gc2 GEMM (h1 @ Wgc2 -> G2 bf16) where A = relu(S1*scale+shift) applied
// during register-staged LDS write. Wgc2t layout [n=128][k=256] -> ldB = 256.
__global__ __launch_bounds__(256) void k_mm_gc2(const u16* __restrict__ A, const u16* __restrict__ Bt,
                                                const float* __restrict__ scale,
                                                const float* __restrict__ shift,
                                                u16* __restrict__ C, int M) {
    __shared__ __align__(16) u16 As[128 * 32];
    __shared__ __align__(16) u16 Bs[128 * 32];
    int m0 = blockIdx.x * 128;
    int t = threadIdx.x, w = t >> 6, l = t & 63;
    int wr = (w >> 1) * 64, wc = (w & 1) * 64;
    int aoff = (wr + (l & 15)) * 32 + (l >> 4) * 8;
    int boff = (wc + (l & 15)) * 32 + (l >> 4) * 8;
    f32x4 acc[4][4]; mm_zero(acc);
    for (int k0 = 0; k0 < 256; k0 += 32) {
        short8 av[2];
        #pragma unroll
        for (int s = 0; s < 2; ++s) {
            int i = s * 256 + t;
            int row = i >> 2, ch = i & 3;
            int col = k0 + ch * 8;
            short8 v = *(const short8*)(A + (size_t)(m0 + row) * 256 + col);
            float4 sa = *(const float4*)(scale + col);
            float4 sb = *(const float4*)(scale + col + 4);
            float4 ha = *(const float4*)(shift + col);
            float4 hb = *(const float4*)(shift + col + 4);
            short8 o;
            o[0] = (short)f2bf(fmaxf(bf2f((u16)v[0]) * sa.x + ha.x, 0.f));
            o[1] = (short)f2bf(fmaxf(bf2f((u16)v[1]) * sa.y + ha.y, 0.f));
            o[2] = (short)f2bf(fmaxf(bf2f((u16)v[2]) * sa.z + ha.z, 0.f));
            o[3] = (short)f2bf(fmaxf(bf2f((u16)v[3]) * sa.w + ha.w, 0.f));
            o[4] = (short)f2bf(fmaxf(bf2f((u16)v[4]) * sb.x + hb.x, 0.f));
            o[5] = (short)f2bf(fmaxf(bf2f((u16)v[5]) * sb.y + hb.y, 0.f));
            o[6] = (short)f2bf(fmaxf(bf2f((u16)v[6]) * sb.z + hb.z, 0.f));
            o[7] = (short)f2bf(fmaxf(bf2f((u16)v[7]) * sb.w + hb.w, 0.f));
            av[s] = o;
        }
        __syncthreads();
        #pragma unroll
        for (int s = 0; s < 2; ++s) {
            int i = s * 256 + t;
            *(short8*)(As + i * 8) = av[s];
            int row = i >> 2, ch = i & 3;
            GLOAD16(Bt + (size_t)row * 256 + k0 + ch * 8, Bs + i * 8);
        }
        __syncthreads();
        short8 af[4], bfr[4];
        #pragma unroll
        for (int i = 0; i < 4; ++i) af[i] = *(const short8*)(As + aoff + i * 16 * 32);
        #pragma unroll
        for (int j = 0; j < 4; ++j) bfr[j] = *(const short8*)(Bs + boff + j * 16 * 32);
        #pragma unroll
        for (int i = 0; i < 4; ++i)
            #pragma unroll
            for (int j = 0; j < 4; ++j)
                acc[i][j] = __builtin_amdgcn_mfma_f32_16x16x32_bf16(af[i], bfr[j], acc[i][j], 0, 0, 0);
    }
    int rbase = m0 + (w >> 1) * 64 + (l >> 4) * 4;
    int cbase = (w & 1) * 64 + (l & 15);
    #pragma unroll
    for (int j = 0; j < 4; ++j)
        #pragma unroll
        for (int i = 0; i < 4; ++i)
            #pragma unroll
            for (int r = 0; r < 4; ++r) {
                int row = rbase + i * 16 + r;
                if (row < M) C[(size_t)row * 128 + cbase + j * 16] = f2bf(acc[i][j][r]);
            }
}

// gating GEMM with fused row-LN + relu + Wg2 dot + softmax -> gate[N][2]
__global__ __launch_bounds__(256) void k_mm_gate(const u16* A0, const u16* A1, const u16* A2,
                                                 const u16* B0, const u16* B1, const u16* B2,
                                                 const float* __restrict__ bg1,
                                                 const float* __restrict__ wlast,
                                                 const float* __restrict__ deg,
                                                 const float* __restrict__ ln_g,
                                                 const float* __restrict__ ln_b,
                                                 const float* __restrict__ Wg2,
                                                 const float* __restrict__ bg2,
                                                 float* __restrict__ gate, int M) {
    __shared__ __align__(16) u16 As[128 * 32];
    __shared__ __align__(16) u16 Bs[128 * 32];
    __shared__ float ps1[2][128], ps2[2][128], pt0[2][128], pt1[2][128];
    int m0 = blockIdx.x * 128;
    f32x4 acc[4][4]; mm_zero(acc);
    mm_core(A0, B0, 256, 256, 256, m0, 0, As, Bs, acc);
    mm_core(A1, B1, 256, 256, 256, m0, 0, As, Bs, acc);
    mm_core(A2, B2, 256, 256, 256, m0, 0, As, Bs, acc);
    int t = threadIdx.x, w = t >> 6, l = t & 63;
    int hcol = w & 1;
    int lr0 = (w >> 1) * 64 + (l >> 4) * 4;
    int cbase = hcol * 64 + (l & 15);
    float wl[4], bg[4], lg[4], lb[4], wa[4], wb_[4];
    #pragma unroll
    for (int j = 0; j < 4; ++j) {
        int col = cbase + j * 16;
        wl[j] = wlast[col]; bg[j] = bg1[col];
        lg[j] = ln_g[col];  lb[j] = ln_b[col];
        wa[j] = Wg2[col * 2 + 0]; wb_[j] = Wg2[col * 2 + 1];
    }
    #pragma unroll
    for (int i = 0; i < 4; ++i)
        #pragma unroll
        for (int r = 0; r < 4; ++r) {
            int row = m0 + lr0 + i * 16 + r;
            float dgv = (row < M) ? deg[row] : 0.f;
            float s1 = 0.f, s2 = 0.f;
            #pragma unroll
            for (int j = 0; j < 4; ++j) {
                float h = acc[i][j][r] + bg[j] + dgv * wl[j];
                acc[i][j][r] = h;
                s1 += h; s2 += h * h;
            }
            s1 = rsum16(s1); s2 = rsum16(s2);
            if ((l & 15) == 0) { ps1[hcol][lr0 + i * 16 + r] = s1; ps2[hcol][lr0 + i * 16 + r] = s2; }
        }
    __syncthreads();
    #pragma unroll
    for (int i = 0; i < 4; ++i)
        #pragma unroll
        for (int r = 0; r < 4; ++r) {
            int lr = lr0 + i * 16 + r;
            float s1 = ps1[0][lr] + ps1[1][lr];
            float s2 = ps2[0][lr] + ps2[1][lr];
            float mu = s1 * (1.f / 128.f);
            float var = s2 * (1.f / 128.f) - mu * mu;
            float is = 1.0f / sqrtf(var + 1e-5f);
            float t0 = 0.f, t1 = 0.f;
            #pragma unroll
            for (int j = 0; j < 4; ++j) {
                float y = fmaxf((acc[i][j][r] - mu) * is * lg[j] + lb[j], 0.f);
                t0 += y * wa[j]; t1 += y * wb_[j];
            }
            t0 = rsum16(t0); t1 = rsum16(t1);
            if ((l & 15) == 0) { pt0[hcol][lr] = t0; pt1[hcol][lr] = t1; }
        }
    __syncthreads();
    if (hcol == 0 && (l & 15) == 0) {
        float b20 = bg2[0], b21 = bg2[1];
        #pragma unroll
        for (int i = 0; i < 4; ++i)
            #pragma unroll
            for (int r = 0; r < 4; ++r) {
                int lr = lr0 + i * 16 + r;
                int row = m0 + lr;
                if (row >= M) continue;
                float t0 = (pt0[0][lr] + pt0[1][lr] + b20) * 0.5f;
                float t1 = (pt1[0][lr] + pt1[1][lr] + b21) * 0.5f;
                float m = fmaxf(t0, t1);
                float e0 = __expf(t0 - m), e1 = __expf(t1 - m);
                float inv = 1.0f / (e0 + e1);
                gate[(size_t)row * 2 + 0] = e0 * inv;
                gate[(size_t)row * 2 + 1] = e1 * inv;
            }
    }
}

// x@Wxp+bxp with fused bn2-apply (low = relu(S2*scale+shift), written here)
// and residual-LN -> resid (bf16).
__global__ __launch_bounds__(256) void k_mm_xp(const u16* __restrict__ A, const u16* __restrict__ Bt,
                                               const float* __restrict__ bias,
                                               const u16* __restrict__ S2,
                                               const float* __restrict__ scale,
                                               const float* __restrict__ shift,
                                               const float* __restrict__ g,
                                               const float* __restrict__ b,
                                               const float* __restrict__ rs_ptr,
                                               float* __restrict__ low_out,
                                               u16* __restrict__ resid, int M) {
    __shared__ __align__(16) u16 As[128 * 32];
    __shared__ __align__(16) u16 Bs[128 * 32];
    __shared__ float ps1[2][128], ps2[2][128];
    int m0 = blockIdx.x * 128;
    f32x4 acc[4][4]; mm_zero(acc);
    mm_core(A, Bt, 256, 256, 256, m0, 0, As, Bs, acc);
    int t = threadIdx.x, w = t >> 6, l = t & 63;
    int hcol = w & 1;
    int lr0 = (w >> 1) * 64 + (l >> 4) * 4;
    int cbase = hcol * 64 + (l & 15);
    float rs = rs_ptr[0];
    float bx[4], lg[4], lb[4], sc_[4], sh_[4];
    #pragma unroll
    for (int j = 0; j < 4; ++j) {
        int col = cbase + j * 16;
        bx[j] = bias[col]; lg[j] = g[col]; lb[j] = b[col];
        sc_[j] = scale[col]; sh_[j] = shift[col];
    }
    #pragma unroll
    for (int i = 0; i < 4; ++i)
        #pragma unroll
        for (int r = 0; r < 4; ++r) {
            int row = m0 + lr0 + i * 16 + r;
            float s1 = 0.f, s2 = 0.f;
            #pragma unroll
            for (int j = 0; j < 4; ++j) {
                float lv = 0.f;
                if (row < M) {
                    float s2v = bf2f(S2[(size_t)row * 128 + cbase + j * 16]);
                    lv = fmaxf(s2v * sc_[j] + sh_[j], 0.f);
                    low_out[(size_t)row * 128 + cbase + j * 16] = lv;
                }
                float h = rs * (acc[i][j][r] + bx[j] - lv);
                acc[i][j][r] = h;
                s1 += h; s2 += h * h;
            }
            s1 = rsum16(s1); s2 = rsum16(s2);
            if ((l & 15) == 0) { ps1[hcol][lr0 + i * 16 + r] = s1; ps2[hcol][lr0 + i * 16 + r] = s2; }
        }
    __syncthreads();
    #pragma unroll
    for (int i = 0; i < 4; ++i)
        #pragma unroll
        for (int r = 0; r < 4; ++r) {
            int lr = lr0 + i * 16 + r;
            int row = m0 + lr;
            float s1 = ps1[0][lr] + ps1[1][lr];
            float s2 = ps2[0][lr] + ps2[1][lr];
            float mu = s1 * (1.f / 128.f);
            float var = s2 * (1.f / 128.f) - mu * mu;
            float is = 1.0f / sqrtf(var + 1e-5f);
            if (row < M) {
                #pragma unroll
                for (int j = 0; j < 4; ++j) {
                    float y = (acc[i][j][r] - mu) * is * lg[j] + lb[j];
                    resid[(size_t)row * 128 + cbase + j * 16] = f2bf(y);
                }
            }
        }
}

// Q -> bf16 Qb; K/V -> bf16 interleaved KV[N][256]
__global__ __launch_bounds__(256) void k_mm_qkv(const u16* __restrict__ A,
                                                const u16* Wqt, const u16* Wkt, const u16* Wvt,
                                                u16* Qb, u16* KV, int M) {
    __shared__ __align__(16) u16 As[128 * 32];
    __shared__ __align__(16) u16 Bs[128 * 32];
    int z = blockIdx.z;
    const u16* Bt = (z == 0) ? Wqt : (z == 1) ? Wkt : Wvt;
    int m0 = blockIdx.x * 128;
    f32x4 acc[4][4]; mm_zero(acc);
    mm_core(A, Bt, 128, 128, 128, m0, 0, As, Bs, acc);
    int t = threadIdx.x, w = t >> 6, l = t & 63;
    int rbase = m0 + (w >> 1) * 64 + (l >> 4) * 4;
    int cbase = (w & 1) * 64 + (l & 15);
    if (z == 0) {
        #pragma unroll
        for (int j = 0; j < 4; ++j)
            #pragma unroll
            for (int i = 0; i < 4; ++i)
                #pragma unroll
                for (int r = 0; r < 4; ++r) {
                    int row = rbase + i * 16 + r;
                    if (row < M) Qb[(size_t)row * 128 + cbase + j * 16] = f2bf(acc[i][j][r]);
                }
    } else {
        int coff = (z == 1) ? 0 : 128;
        #pragma unroll
        for (int j = 0; j < 4; ++j)
            #pragma unroll
            for (int i = 0; i < 4; ++i)
                #pragma unroll
                for (int r = 0; r < 4; ++r) {
                    int row = rbase + i * 16 + r;
                    if (row < M) KV[(size_t)row * 256 + coff + cbase + j * 16] = f2bf(acc[i][j][r]);
                }
    }
}

// ---------------------------------------------------------------------------
// BatchNorm (bf16 input) — bn2 stats only (apply fused into k_mm_xp)
// ---------------------------------------------------------------------------
__global__ void k_bn_stats_bf(const u16* __restrict__ H, double* __restrict__ stats, int N, int C) {
    int t = threadIdx.x;
    int rpt = 256 / C;
    int rsub = t / C;
    int col = t - rsub * C;
    double s = 0.0, q = 0.0;
    for (long r = (long)blockIdx.x * rpt + rsub; r < N; r += (long)gridDim.x * rpt) {
        float v = bf2f(H[(size_t)r * C + col]);
        s += v; q += (double)v * v;
    }
    __shared__ double sh_s[256], sh_q[256];
    sh_s[t] = s; sh_q[t] = q;
    __syncthreads();
    if (t < C) {
        for (int k = 1; k < rpt; ++k) { s += sh_s[t + k * C]; q += sh_q[t + k * C]; }
        atomicAdd(&stats[t], s);
        atomicAdd(&stats[C + t], q);
    }
}

__global__ void k_bn_fin(const double* __restrict__ stats, const float* __restrict__ g,
                         const float* __restrict__ b, float* __restrict__ scale,
                         float* __restrict__ shift, int C, double invN) {
    int t = threadIdx.x;
    if (t >= C) return;
    double mean = stats[t] * invN;
    double var = stats[C + t] * invN - mean * mean;
    float sc = (float)((double)g[t] / sqrt(var + 1e-5));
    scale[t] = sc;
    shift[t] = b[t] - (float)mean * sc;
}

// ---------------------------------------------------------------------------
// fused attention: 8 edges/iter, 16-lane groups for score, KV interleaved,
// Q read as bf16 — R8-measured best variant (no nt hints: A/B showed nt hurt)
// ---------------------------------------------------------------------------
__global__ void k_attn_aggr(const u16* __restrict__ Qb, const u16* __restrict__ KV,
                            const int* __restrict__ row_ptr, const int2* __restrict__ cv,
                            const float* __restrict__ gate, const float* __restrict__ low,
                            float* __restrict__ high, float* __restrict__ outp, int N) {
    int wid = blockIdx.x * 4 + (threadIdx.x >> 6);
    if (wid >= N) return;
    int lane = threadIdx.x & 63;
    int sub = lane & 15;
    int g = lane >> 4;
    float qs[8];
    {
        short8 q8 = *(const short8*)(Qb + (size_t)wid * HD + sub * 8);
        #pragma unroll
        for (int k = 0; k < 8; ++k) qs[k] = bf2f((u16)q8[k]);
    }
    float2 qv;
    {
        ushort2 qt = *(const ushort2*)(Qb + (size_t)wid * HD + lane * 2);
        qv.x = bf2f(qt.x); qv.y = bf2f(qt.y);
    }
    float n0 = 0, n1 = 0, den = 0;
    int s = row_ptr[wid], e = row_ptr[wid + 1];
    int j = s;
    for (; j + 7 < e; j += 8) {
        int cg0 = cv[j + g].x;
        int cg1 = cv[j + 4 + g].x;
        short8 ka = *(const short8*)(KV + (size_t)cg0 * 256 + sub * 8);
        short8 kb = *(const short8*)(KV + (size_t)cg1 * 256 + sub * 8);
        float p0 = qs[0] * bf2f((u16)ka[0]) + qs[1] * bf2f((u16)ka[1])
                 + qs[2] * bf2f((u16)ka[2]) + qs[3] * bf2f((u16)ka[3])
                 + qs[4] * bf2f((u16)ka[4]) + qs[5] * bf2f((u16)ka[5])
                 + qs[6] * bf2f((u16)ka[6]) + qs[7] * bf2f((u16)ka[7]);
        float p1 = qs[0] * bf2f((u16)kb[0]) + qs[1] * bf2f((u16)kb[1])
                 + qs[2] * bf2f((u16)kb[2]) + qs[3] * bf2f((u16)kb[3])
                 + qs[4] * bf2f((u16)kb[4]) + qs[5] * bf2f((u16)kb[5])
                 + qs[6] * bf2f((u16)kb[6]) + qs[7] * bf2f((u16)kb[7]);
        p0 += __shfl_xor(p0, 1); p1 += __shfl_xor(p1, 1);
        p0 += __shfl_xor(p0, 2); p1 += __shfl_xor(p1, 2);
        p0 += __shfl_xor(p0, 4); p1 += __shfl_xor(p1, 4);
        p0 += __shfl_xor(p0, 8); p1 += __shfl_xor(p1, 8);
        float sc0 = p0 * 0.08838834764831845f;
        float sc1 = p1 * 0.08838834764831845f;
        float ls0 = sc0 > 0.f ? sc0 : 0.2f * sc0;
        float ls1 = sc1 > 0.f ? sc1 : 0.2f * sc1;
        float ex0 = __expf(ls0);
        float ex1 = __expf(ls1);
        float exb[8]; int cb[8];
        #pragma unroll
        for (int t = 0; t < 4; ++t) {
            exb[t]     = __shfl(ex0, t << 4); cb[t]     = __shfl(cg0, t << 4);
            exb[4 + t] = __shfl(ex1, t << 4); cb[4 + t] = __shfl(cg1, t << 4);
        }
        ushort2 vb[8];
        #pragma unroll
        for (int t = 0; t < 8; ++t) vb[t] = *(const ushort2*)(KV + (size_t)cb[t] * 256 + 128 + lane * 2);
        #pragma unroll
        for (int t = 0; t < 8; ++t) {
            n0 += exb[t] * bf2f(vb[t].x);
            n1 += exb[t] * bf2f(vb[t].y);
            den += exb[t];
        }
    }
    for (; j + 3 < e; j += 4) {
        int cg = cv[j + g].x;
        short8 kk = *(const short8*)(KV + (size_t)cg * 256 + sub * 8);
        float p = qs[0] * bf2f((u16)kk[0]) + qs[1] * bf2f((u16)kk[1])
                + qs[2] * bf2f((u16)kk[2]) + qs[3] * bf2f((u16)kk[3])
                + qs[4] * bf2f((u16)kk[4]) + qs[5] * bf2f((u16)kk[5])
                + qs[6] * bf2f((u16)kk[6]) + qs[7] * bf2f((u16)kk[7]);
        p += __shfl_xor(p, 1); p += __shfl_xor(p, 2);
        p += __shfl_xor(p, 4); p += __shfl_xor(p, 8);
        float sc = p * 0.08838834764831845f;
        float ls = sc > 0.f ? sc : 0.2f * sc;
        float ex = __expf(ls);
        float exb[4]; int cb[4];
        #pragma unroll
        for (int t = 0; t < 4; ++t) { exb[t] = __shfl(ex, t << 4); cb[t] = __shfl(cg, t << 4); }
        ushort2 vb[4];
        #pragma unroll
        for (int t = 0; t < 4; ++t) vb[t] = *(const ushort2*)(KV + (size_t)cb[t] * 256 + 128 + lane * 2);
        #pragma unroll
        for (int t = 0; t < 4; ++t) {
            n0 += exb[t] * bf2f(vb[t].x);
            n1 += exb[t] * bf2f(vb[t].y);
            den += exb[t];
        }
    }
    for (; j < e; ++j) {
        int c0 = cv[j].x;
        ushort2 kb0 = *(const ushort2*)(KV + (size_t)c0 * 256 + lane * 2);
        ushort2 vb0 = *(const ushort2*)(KV + (size_t)c0 * 256 + 128 + lane * 2);
        float sc0 = qv.x * bf2f(kb0.x) + qv.y * bf2f(kb0.y);
        #pragma unroll
        for (int off = 32; off > 0; off >>= 1) sc0 += __shfl_xor(sc0, off);
        float p = sc0 * 0.08838834764831845f;
        float ls = p > 0.f ? p : 0.2f * p;
        float ex = __expf(ls);
        n0 += ex * bf2f(vb0.x); n1 += ex * bf2f(vb0.y); den += ex;
    }
    float inv = 1.0f / (den + 1e-16f);
    float h0 = n0 * inv, h1 = n1 * inv;
    *(float2*)(high + (size_t)wid * HD + lane * 2) = make_float2(h0, h1);
    float g0 = gate[(size_t)wid * 2 + 0], g1 = gate[(size_t)wid * 2 + 1];
    float2 lw = *(const float2*)(low + (size_t)wid * HD + lane * 2);
    *(float2*)(outp + (size_t)wid * HD + lane * 2) = make_float2(g0 * lw.x + g1 * h0, g0 * lw.y + g1 * h1);
}

// ---------------------------------------------------------------------------
extern "C" void kernel_launch(void* const* d_in, const int* in_sizes, int n_in,
                              void* d_out, int out_size, void* d_ws, size_t ws_size,
                              hipStream_t stream) {
    const float* x      = (const float*)d_in[0];
    const int*   erow   = (const int*)d_in[1];
    const int*   ecol   = (const int*)d_in[2];
    const float* avals  = (const float*)d_in[3];
    const float* W_gc1  = (const float*)d_in[4];
    const float* bn1_g  = (const float*)d_in[6];
    const float* bn1_b  = (const float*)d_in[7];
    const float* W_gc2  = (const float*)d_in[8];
    const float* bn2_g  = (const float*)d_in[10];
    const float* bn2_b  = (const float*)d_in[11];
    const float* Wg1    = (const float*)d_in[12];
    const float* bg1    = (const float*)d_in[13];
    const float* ln_g   = (const float*)d_in[14];
    const float* ln_b   = (const float*)d_in[15];
    const float* Wg2    = (const float*)d_in[16];
    const float* bg2    = (const float*)d_in[17];
    const float* Wxp    = (const float*)d_in[18];
    const float* bxp    = (const float*)d_in[19];
    const float* rscale = (const float*)d_in[20];
    const float* rn_g   = (const float*)d_in[21];
    const float* rn_b   = (const float*)d_in[22];
    const float* Wq     = (const float*)d_in[23];
    const float* Wk     = (const float*)d_in[24];
    const float* Wv     = (const float*)d_in[25];

    const int N = in_sizes[0] / F0;   // 100000
    const int E = in_sizes[1];        // 3200000

    char* base = (char*)d_ws;
    size_t off = 0;
    auto carve = [&](size_t bytes) -> char* {
        char* p = base + off;
        off += (bytes + 255) & ~(size_t)255;
        return p;
    };
    double* stats  = (double*)carve(4096);
    float* scaleb  = (float*)carve(1024);
    float* shiftb  = (float*)carve(1024);
    int*   partials= (int*)carve(2048);
    u16* Wgc1t = (u16*)carve(65536 * 2);
    u16* Wgc2t = (u16*)carve(32768 * 2);
    u16* Wdt   = (u16*)carve(32768 * 2);
    u16* W1t   = (u16*)carve(32768 * 2);
    u16* W2t   = (u16*)carve(32768 * 2);
    u16* Wxpt  = (u16*)carve(32768 * 2);
    u16* Wqt   = (u16*)carve(16384 * 2);
    u16* Wkt   = (u16*)carve(16384 * 2);
    u16* Wvt   = (u16*)carve(16384 * 2);
    int*   row_ptr = (int*)carve((size_t)(N + 1) * 4);
    int*   cursor  = (int*)carve((size_t)N * 4);   // hist counts
    float* deg     = (float*)carve((size_t)N * 4);
    int2*  cv      = (int2*)carve((size_t)E * 8);        // packed (col, val)
    u16*   x_bf    = (u16*)carve((size_t)NP * F0 * 2);
    u16*   kvb     = (u16*)carve((size_t)NP * 256 * 2);  // KV interleaved [N][256]
    u16*   AX_bf   = (u16*)carve((size_t)NP * F0 * 2);
    u16*   XSTD_bf = (u16*)carve((size_t)NP * F0 * 2);
    u16*   h1_bf   = (u16*)carve((size_t)NP * F0 * 2);   // S1 bf16 -> resid
    u16*   S2_bf   = (u16*)carve((size_t)NP * HD * 2);
    u16*   G2_bf   = (u16*)carve((size_t)NP * HD * 2);
    float* M3      = (float*)carve((size_t)NP * HD * 4); // rank -> Qb
    (void)ws_size; (void)n_in; (void)out_size;

    u16*   S1_bf = h1_bf;
    u16*   resid_bf = h1_bf;                       // S1 dead after gc2 GEMM
    int*   rank  = (int*)M3;                       // dead after scatter
    u16*   Qb    = (u16*)M3;                       // live from mm_qkv on

    float* out_o    = (float*)d_out;
    float* out_gate = out_o + (size_t)N * HD;
    float* out_low  = out_gate + (size_t)N * 2;
    float* out_high = out_low + (size_t)N * HD;

    const int eb  = (E + 255) / 256;
    const int wb  = (N + 3) / 4;
    const int NB1 = (N + 1023) / 1024;
    const int gx  = (N + 127) / 128;
    const dim3 blk(256);

    // ===== CSR (hist+rank -> scan -> atomic-free scatter) =====
    hipMemsetAsync(cursor, 0, (size_t)N * 4, stream);
    k_hist_rank<<<eb, blk, 0, stream>>>(erow, cursor, rank, E);
    k_scan_blk<<<NB1, 1024, 0, stream>>>(cursor, row_ptr + 1, partials, N);
    k_scan_part<<<1, 128, 0, stream>>>(partials, NB1);
    k_scan_add<<<NB1, 1024, 0, stream>>>(row_ptr, partials, N);
    k_scatter_direct<<<eb, blk, 0, stream>>>(erow, ecol, avals, rank, row_ptr, cv, E);

    // ===== casts =====
    k_cast_x<<<(N * 64 + 255) / 256, blk, 0, stream>>>(x, x_bf, N * 64);
    k_prep_w<<<dim3(256, 1, 9), blk, 0, stream>>>(W_gc1, W_gc2, Wg1, Wxp, Wq, Wk, Wv,
                                                  Wgc1t, Wgc2t, Wdt, W1t, W2t, Wxpt, Wqt, Wkt, Wvt);

    // ===== spmm over x (fused finalize: AX_bf, XSTD_bf, deg directly) =====
    k_spmm_x2<<<wb, blk, 0, stream>>>(x_bf, row_ptr, cv, AX_bf, XSTD_bf, deg, N);

    // ===== low path (bn1 stats fused in gc1; bn1 apply fused in gc2 staging) =====
    hipMemsetAsync(stats, 0, 4096, stream);
    k_mm_gc1<<<dim3(gx, 2), blk, 0, stream>>>(AX_bf, Wgc1t, S1_bf, stats, N);
    k_bn_fin<<<1, blk, 0, stream>>>(stats, bn1_g, bn1_b, scaleb, shiftb, 256, 1.0 / N);
    k_mm_gc2<<<dim3(gx, 1), blk, 0, stream>>>(S1_bf, Wgc2t, scaleb, shiftb, G2_bf, N);
    k_spmm128<<<wb, blk, 0, stream>>>(G2_bf, row_ptr, cv, S2_bf, N);
    hipMemsetAsync(stats, 0, 2048, stream);
    k_bn_stats_bf<<<1024, blk, 0, stream>>>(S2_bf, stats, N, 128);
    k_bn_fin<<<1, blk, 0, stream>>>(stats, bn2_g, bn2_b, scaleb, shiftb, 128, 1.0 / N);

    // ===== gating (fused GEMM + LN + softmax) =====
    k_mm_gate<<<dim3(gx, 1), blk, 0, stream>>>(x_bf, AX_bf, XSTD_bf, Wdt, W1t, W2t,
                                               bg1, Wg1 + (size_t)768 * 128, deg,
                                               ln_g, ln_b, Wg2, bg2, out_gate, N);

    // ===== high path (bn2 apply + low write fused into xp) =====
    k_mm_xp<<<dim3(gx, 1), blk, 0, stream>>>(x_bf, Wxpt, bxp, S2_bf, scaleb, shiftb,
                                             rn_g, rn_b, rscale, out_low, resid_bf, N);
    k_mm_qkv<<<dim3(gx, 1, 3), blk, 0, stream>>>(resid_bf, Wqt, Wkt, Wvt, Qb, kvb, N);
    k_attn_aggr<<<wb, blk, 0, stream>>>(Qb, kvb, row_ptr, cv, out_gate, out_low, out_high, out_o, N);
}